// Round 11
// baseline (361.670 us; speedup 1.0000x reference)
//
#include <hip/hip_runtime.h>
#include <hip/hip_fp16.h>
#include <cstdint>
#include <cstddef>

// NUFFT type-2, torchkbnufft-compatible (J=6, alpha=14.04, os=2).
// Pipeline (5 phases, 16 coil-images each, 320x320 -> 640x640):
//   taps:   KB weights + [kh_base, 6 wrapped kw indices] per (phase,point)
//   stageA: ALL phases, apodize+pad rows, reg-FFT-640 along W -> AT[pi][kw][h] fp16.
//           256-thread blocks (R9-proven; R10's 512t regressed 62->72us), 16
//           rows/block, 4 waves x 4 FFTs with HOISTED per-wave twiddle state
//           (wk chain + butterfly twiddles are lane-only -> computed once,
//           reused for all 4 rows; ~170 VALU/FFT saved). LDS stride 709.
//   per phase p:
//     stageB: reg-FFT-640 along H -> G_p[i][kw][kh] fp16, rows PADDED to 648
//             (kh 0..5 mirrored at 640..645). 2 columns/wave (Tw amortized).
//             XCD-PINNED per image (i on XCD i%8, 1.64MB grid in 4MB L2).
//     interp: 6 columns x 4 uint2 loads (6 consecutive padded kh) = 24 aligned
//             8B loads/point; same XCD pinning; sched_barrier keeps MLP.
// FFT-640 = four-step 10x64 in registers: zero-padded FFT-10 (2x FFT-5), twiddle,
// 6 __shfl_xor butterfly stages with sign-fold + lane-conditional twiddle.
// fp16 storage: rel err ~5e-4 << 4.06e-2 threshold (measured absmax 0.0078).

#define PI_F     3.14159265358979323846f
#define KB_ALPHA 14.04f
#define NPH  5
#define NIMG 16
#define NH   320
#define NK   640
#define NKP  648   // padded G row stride (uint32 elems); 640..645 mirror 0..5
#define KLEN 16000

__device__ __forceinline__ uint32_t f2_to_h2(float2 v) {
  union { __half2 h; uint32_t u; } cv;
  cv.h = __float22half2_rn(v);
  return cv.u;
}
__device__ __forceinline__ float2 h2_to_f2(uint32_t u) {
  union { uint32_t u; __half2 h; } cv;
  cv.u = u;
  return __half22float2(cv.h);
}

// ---- modified Bessel I0 (A&S 9.8.1 / 9.8.2, rel err ~2e-7). I0(alpha) cancels
// between apodization (numerator) and tap weights (denominator). ----
__device__ __forceinline__ float i0f(float x) {
  if (x < 3.75f) {
    float t = x * (1.0f / 3.75f), t2 = t * t;
    return 1.0f + t2 * (3.5156229f + t2 * (3.0899424f + t2 * (1.2067492f +
                 t2 * (0.2659732f + t2 * (0.0360768f + t2 * 0.0045813f)))));
  }
  float t = 3.75f / x;
  float poly = 0.39894228f + t * (0.01328592f + t * (0.00225319f + t * (-0.00157565f +
               t * (0.00916281f + t * (-0.02057706f + t * (0.02635537f +
               t * (-0.01647633f + t * 0.00392377f)))))));
  return expf(x) * rsqrtf(x) * poly;
}

// apodization scale (1/FT(KB)); z^2 = alpha^2-(pi*J*u)^2 > 0 always for |u|<=0.25
__device__ __forceinline__ float apodf(int n) {
  float u = (float)(n - 160) * (1.0f / 640.0f);
  float pj = PI_F * 6.0f * u;
  float z = sqrtf(KB_ALPHA * KB_ALPHA - pj * pj);
  float sh = 0.5f * (expf(z) - expf(-z));     // sinh(z)
  return z * i0f(KB_ALPHA) / (6.0f * sh);     // 1/ft = z*I0a/(J*sinh z)
}

__device__ __forceinline__ float2 cadd(float2 a, float2 b) { return make_float2(a.x + b.x, a.y + b.y); }
__device__ __forceinline__ float2 cmul(float2 a, float2 b) {
  return make_float2(fmaf(a.x, b.x, -a.y * b.y), fmaf(a.x, b.y, a.y * b.x));
}
__device__ __forceinline__ float2 cxmad(float2 a, float2 w, float2 x) {
  a.x = fmaf(w.x, x.x, fmaf(-w.y, x.y, a.x));
  a.y = fmaf(w.x, x.y, fmaf( w.y, x.x, a.y));
  return a;
}

// direct 5-point DFT, forward (W5 = e^{-2pi i/5})
__device__ __forceinline__ void fft5(const float2 b[5], float2 z[5]) {
  const float2 w1 = make_float2( 0.309016994374947424f, -0.951056516295153572f);
  const float2 w2 = make_float2(-0.809016994374947424f, -0.587785252292473129f);
  const float2 w3 = make_float2(-0.809016994374947424f,  0.587785252292473129f);
  const float2 w4 = make_float2( 0.309016994374947424f,  0.951056516295153572f);
  z[0] = cadd(cadd(b[0], b[1]), cadd(cadd(b[2], b[3]), b[4]));
  z[1] = b[0]; z[1] = cxmad(z[1], w1, b[1]); z[1] = cxmad(z[1], w2, b[2]); z[1] = cxmad(z[1], w3, b[3]); z[1] = cxmad(z[1], w4, b[4]);
  z[2] = b[0]; z[2] = cxmad(z[2], w2, b[1]); z[2] = cxmad(z[2], w4, b[2]); z[2] = cxmad(z[2], w1, b[3]); z[2] = cxmad(z[2], w3, b[4]);
  z[3] = b[0]; z[3] = cxmad(z[3], w3, b[1]); z[3] = cxmad(z[3], w1, b[2]); z[3] = cxmad(z[3], w4, b[3]); z[3] = cxmad(z[3], w2, b[4]);
  z[4] = b[0]; z[4] = cxmad(z[4], w4, b[1]); z[4] = cxmad(z[4], w3, b[2]); z[4] = cxmad(z[4], w2, b[3]); z[4] = cxmad(z[4], w1, b[4]);
}

// Hoisted per-wave (lane-only) twiddle state, reused across FFTs done by a wave.
struct Tw {
  float2 wk[9];    // W640^{lane*k}, k=1..9
  float2 twl[5];   // butterfly stage twiddle (identity (1,0) on lower lanes)
  float  sgn[6];   // per-stage sign (incl. final half=1 stage)
};
__device__ __forceinline__ void make_tw(int lane, Tw& T) {
  float sn, cs;
  __sincosf(-2.0f * PI_F * (float)lane * (1.0f / 640.0f), &sn, &cs);
  float2 w1 = make_float2(cs, sn);
  T.wk[0] = w1;
#pragma unroll
  for (int k = 1; k < 9; k++) T.wk[k] = cmul(T.wk[k - 1], w1);
#pragma unroll
  for (int j = 0; j < 5; j++) {
    int half = 32 >> j;
    int up = lane & half;
    float ang = -(PI_F / (float)half) * (float)(lane & (half - 1));
    float ss, cc;
    __sincosf(ang, &ss, &cc);
    T.sgn[j] = up ? -1.0f : 1.0f;
    T.twl[j] = make_float2(up ? cc : 1.0f, up ? ss : 0.0f);
  }
  T.sgn[5] = (lane & 1) ? -1.0f : 1.0f;
}

// Register FFT-640 of the zero-padded sequence x[64*n1 + lane] = b[n1] (n1=0..4;
// n1=5..9 implicitly zero). Returns k2 = bitrev6(lane); v[k1] = X[k1 + 10*k2].
__device__ __forceinline__ int fft640_reg(const float2 b[5], float2 v[10], int lane,
                                          const Tw& T) {
  // FFT-10 with upper half zero: even outputs FFT5(b), odd outputs FFT5(b .* W10^n)
  const float2 t1 = make_float2( 0.809016994374947424f, -0.587785252292473129f); // W10^1
  const float2 t2 = make_float2( 0.309016994374947424f, -0.951056516295153572f); // W10^2
  const float2 t3 = make_float2(-0.309016994374947424f, -0.951056516295153572f); // W10^3
  const float2 t4 = make_float2(-0.809016994374947424f, -0.587785252292473129f); // W10^4
  float2 e[5], o[5], bp[5];
  fft5(b, e);
  bp[0] = b[0]; bp[1] = cmul(b[1], t1); bp[2] = cmul(b[2], t2);
  bp[3] = cmul(b[3], t3); bp[4] = cmul(b[4], t4);
  fft5(bp, o);
  v[0] = e[0]; v[2] = e[1]; v[4] = e[2]; v[6] = e[3]; v[8] = e[4];
  v[1] = o[0]; v[3] = o[1]; v[5] = o[2]; v[7] = o[3]; v[9] = o[4];
  // twiddle: v[k1] *= W640^{lane*k1} (hoisted)
#pragma unroll
  for (int k = 1; k < 10; k++) v[k] = cmul(v[k], T.wk[k - 1]);
  // cross-lane FFT-64 over n2=lane: DIF radix-2, 6 shuffle stages, bitrev output.
#pragma unroll
  for (int j = 0; j < 5; j++) {
    int half = 32 >> j;
    float sgn = T.sgn[j];
    float2 twl = T.twl[j];
#pragma unroll
    for (int q = 0; q < 10; q++) {
      float2 oth;
      oth.x = __shfl_xor(v[q].x, half, 64);
      oth.y = __shfl_xor(v[q].y, half, 64);
      float2 t = make_float2(fmaf(sgn, v[q].x, oth.x), fmaf(sgn, v[q].y, oth.y));
      v[q] = cmul(t, twl);
    }
  }
  {  // final stage half=1: twiddle is identity everywhere — adds/subs only
    float sgn = T.sgn[5];
#pragma unroll
    for (int q = 0; q < 10; q++) {
      float2 oth;
      oth.x = __shfl_xor(v[q].x, 1, 64);
      oth.y = __shfl_xor(v[q].y, 1, 64);
      v[q] = make_float2(fmaf(sgn, v[q].x, oth.x), fmaf(sgn, v[q].y, oth.y));
    }
  }
  return __brev(lane) >> 26;
}

// ---- stage A: ALL phases. 16 rows/block; 4 waves x 4 sequential row-FFTs
// (hoisted Tw reused across the 4 rows), fp16 LDS staging (stride 709 >= 703
// required by 11*k2+k1 layout), transposed write = full 64B lines.
// grid = 5*16*20 = 1600 blocks x 256 ----
#define ASTR 709
__global__ __launch_bounds__(256) void stageA_kernel(const float* __restrict__ img,
                                                     uint32_t* __restrict__ AT) {
  __shared__ uint32_t lds[16 * ASTR];   // 45,376 B fp16-pairs
  int wv = threadIdx.x >> 6, lane = threadIdx.x & 63;
  int bx = blockIdx.x;
  int p = bx / (NIMG * 20);
  int rem = bx - p * (NIMG * 20);
  int i = rem / 20, hg = rem - i * 20;
  int h0 = hg * 16;
  const float2* base = (const float2*)img + (size_t)(p * NIMG + i) * NH * NH;
  Tw T;
  make_tw(lane, T);
  // w-apodization is row-invariant: compute the 5 lane scales once
  float aw[5];
#pragma unroll
  for (int j = 0; j < 5; j++) aw[j] = apodf(lane + 64 * j) * (1.0f / 640.0f);
  // 4 sequential row FFTs per wave: rows r = wv*4 + t
#pragma unroll 1
  for (int t = 0; t < 4; t++) {
    int r = wv * 4 + t;
    int h = h0 + r;
    const float2* src = base + (size_t)h * NH;
    float ah = apodf(h);
    float2 b[5];
#pragma unroll
    for (int j = 0; j < 5; j++) {
      float2 x = src[lane + 64 * j];
      float sc = aw[j] * ah;
      b[j] = make_float2(x.x * sc, x.y * sc);
    }
    float2 v[10];
    int k2 = fft640_reg(b, v, lane, T);
    uint32_t* rowl = lds + r * ASTR + 11 * k2;   // kw=k1+10*k2 at 11*k2+k1 (max 702 < 709)
#pragma unroll
    for (int k = 0; k < 10; k++) rowl[k] = f2_to_h2(v[k]);
  }
  __syncthreads();
  // transposed write: AT[kw][h0+c], c = tid&15 -> 16 consecutive h = 64B line
  int c = threadIdx.x & 15, kwv = threadIdx.x >> 4;   // kwv in [0,16)
  uint32_t* dst = AT + (size_t)(p * NIMG + i) * NK * NH + h0 + c;
  const uint32_t* srcl = lds + c * ASTR;
#pragma unroll
  for (int s = 0; s < 40; s++) {
    int kw = kwv + 16 * s;
    int q2 = (kw * 6554) >> 16;     // kw/10 (exact for kw<1638)
    int q1 = kw - 10 * q2;
    dst[(size_t)kw * NH] = srcl[11 * q2 + q1];
  }
}

// ---- stage B: column FFTs, pure-register, XCD-PINNED per image, padded rows.
// 2 columns per wave (hoisted Tw amortized). grid = 1280 blocks x 256 per phase;
// bx = 8*J + x, x = XCD = i%8; J<80 -> image x, J>=80 -> image x+8.
// k2==0 lane mirrors kh 0..5 -> 640..645. ----
__global__ __launch_bounds__(256) void stageB_kernel(const uint32_t* __restrict__ AT,
                                                     uint32_t* __restrict__ G, int p) {
  int wv = threadIdx.x >> 6, lane = threadIdx.x & 63;
  int x = blockIdx.x & 7;
  int J = blockIdx.x >> 3;           // 0..159
  int i = x + 8 * (J >= 80);
  int Jp = (J >= 80) ? J - 80 : J;   // 0..79
  Tw T;
  make_tw(lane, T);
#pragma unroll 1
  for (int t = 0; t < 2; t++) {
    int kw = Jp * 8 + wv * 2 + t;
    const uint32_t* rowp = AT + ((size_t)(p * NIMG + i) * NK + kw) * NH;  // contiguous
    float2 b[5];
#pragma unroll
    for (int j = 0; j < 5; j++) b[j] = h2_to_f2(rowp[lane + 64 * j]);
    float2 v[10];
    int k2 = fft640_reg(b, v, lane, T);
    // lane writes 10 consecutive kh as 5 uint2 (pairs of half2); stays in L2
    uint32_t hv[10];
#pragma unroll
    for (int k = 0; k < 10; k++) hv[k] = f2_to_h2(v[k]);
    uint32_t* rowo = G + ((size_t)i * NK + kw) * NKP;
    uint2* dst = (uint2*)(rowo + 10 * k2);
#pragma unroll
    for (int m = 0; m < 5; m++) dst[m] = make_uint2(hv[2 * m], hv[2 * m + 1]);
    if (k2 == 0) {                   // mirror kh 0..5 at 640..645 (no wrap in interp)
      uint2* pd = (uint2*)(rowo + 640);
#pragma unroll
      for (int m = 0; m < 3; m++) pd[m] = make_uint2(hv[2 * m], hv[2 * m + 1]);
    }
  }
}

// ---- taps: per (phase, point): kh weights[6], kw weights[6], phase (c,s) in tapw
// (stride 16 floats); [kh_base, kw_idx[6], pad] in tapi (stride 8 ints, int4x2) ----
__global__ __launch_bounds__(256) void taps_kernel(const float* __restrict__ traj,
                                                   float* __restrict__ tapw,
                                                   int* __restrict__ tapi) {
  int t = blockIdx.x * 256 + threadIdx.x;
  if (t >= NPH * KLEN) return;
  int p = t / KLEN, l = t - p * KLEN;
  float inv_i0a = 1.0f / i0f(KB_ALPHA);
  float* wout = tapw + (size_t)t * 16;
  int* iout = tapi + (size_t)t * 8;
  float ang = 0.0f;
#pragma unroll
  for (int d = 0; d < 2; d++) {
    float om = traj[((size_t)p * 2 + d) * KLEN + l];
    float tt = om * 640.0f / 6.28318530717958647692f;
    float base = floorf(tt - 3.0f);
    ang += om * 160.0f;              // n_shift = 320//2
    if (d == 0) {                    // kh: store base index only (taps consecutive)
      int bi = (int)base + 1 + 640;  // [318, 958]
      if (bi >= 640) bi -= 640;      // [0, 639]
      iout[0] = bi;
    }
#pragma unroll
    for (int j = 0; j < 6; j++) {
      float kf = base + (float)(j + 1);
      float u = tt - kf;
      float arg = fmaxf(1.0f - (u * u) * (1.0f / 9.0f), 0.0f);
      wout[d * 6 + j] = i0f(KB_ALPHA * sqrtf(arg)) * inv_i0a;
      if (d == 1) {                  // kw: individually wrapped indices
        int ki = (int)kf + 640;
        if (ki >= 640) ki -= 640;
        iout[1 + j] = ki;
      }
    }
  }
  float s, c;
  sincosf(ang, &s, &c);              // accurate path: |ang| up to ~1005 rad
  wout[12] = c;
  wout[13] = s;
  wout[14] = 0.f;
  wout[15] = 0.f;
  iout[7] = 0;
}

// ---- interp: XCD-pinned gather from L2-hot padded fp16 G. 2000 blocks x 128.
// Per column: 4 aligned uint2 loads cover the 6 consecutive kh taps (window
// offset off = b0&1 folded into a 7-wide select-built weight vector). ----
__global__ __launch_bounds__(128) void interp_kernel(const uint32_t* __restrict__ G,
                                                     const float* __restrict__ tapw,
                                                     const int* __restrict__ tapi,
                                                     float* __restrict__ out, int p) {
  int x = blockIdx.x & 7;            // XCD (round-robin dispatch heuristic)
  int j = blockIdx.x >> 3;           // 0..249
  int i = x + 8 * (j >= 125);
  int jj = (j >= 125) ? j - 125 : j;
  int l = jj * 128 + threadIdx.x;
  // vectorized tap loads
  const float4* w4 = (const float4*)(tapw + (size_t)(p * KLEN + l) * 16);
  float4 wa = w4[0], wb = w4[1], wc = w4[2], wd = w4[3];
  const int4* i4 = (const int4*)(tapi + (size_t)(p * KLEN + l) * 8);
  int4 ia = i4[0], ib = i4[1];
  float whv[6] = {wa.x, wa.y, wa.z, wa.w, wb.x, wb.y};
  float wwv[6] = {wb.z, wb.w, wc.x, wc.y, wc.z, wc.w};
  int   iwv[6] = {ia.y, ia.z, ia.w, ib.x, ib.y, ib.z};
  int   b0 = ia.x;
  int   e = b0 & ~1, off = b0 & 1;
  // 7-wide shifted kh-weight window (off=0: w0..w5 at 0..5; off=1: at 1..6)
  float we[7];
  we[0] = off ? 0.f    : whv[0];
  we[1] = off ? whv[0] : whv[1];
  we[2] = off ? whv[1] : whv[2];
  we[3] = off ? whv[2] : whv[3];
  we[4] = off ? whv[3] : whv[4];
  we[5] = off ? whv[4] : whv[5];
  we[6] = off ? whv[5] : 0.f;
  const uint32_t* g = G + (size_t)i * (NK * NKP) + e;
  // all 24 loads in flight, then reduce
  uint2 raw[6][4];
#pragma unroll
  for (int jw = 0; jw < 6; jw++) {
    const uint2* col = (const uint2*)(g + iwv[jw] * NKP);
#pragma unroll
    for (int m = 0; m < 4; m++) raw[jw][m] = col[m];
  }
  __builtin_amdgcn_sched_barrier(0);   // don't sink loads into the FMA chain
  float ar = 0.f, ai = 0.f;
#pragma unroll
  for (int jw = 0; jw < 6; jw++) {
    float sr = 0.f, si = 0.f;
#pragma unroll
    for (int k = 0; k < 7; k++) {
      uint32_t u = (k & 1) ? raw[jw][k >> 1].y : raw[jw][k >> 1].x;
      float2 v = h2_to_f2(u);
      sr = fmaf(we[k], v.x, sr);
      si = fmaf(we[k], v.y, si);
    }
    ar = fmaf(wwv[jw], sr, ar);
    ai = fmaf(wwv[jw], si, ai);
  }
  float c = wd.x, s = wd.y;
  size_t o = (size_t)(p * NIMG + i) * KLEN + l;
  ((float2*)out)[o] = make_float2(ar * c - ai * s, ar * s + ai * c);
}

extern "C" void kernel_launch(void* const* d_in, const int* in_sizes, int n_in,
                              void* d_out, int out_size, void* d_ws, size_t ws_size,
                              hipStream_t stream) {
  const float* img  = (const float*)d_in[0];   // (1,5,8,2,320,320,2) f32
  const float* traj = (const float*)d_in[1];   // (5,2,16000) f32
  float* out = (float*)d_out;                  // (1,5,8,2,16000,2) f32

  char* ws = (char*)d_ws;
  float*    tapw = (float*)ws;                       // 5*16000*16*4 = 5,120,000 B
  int*      tapi = (int*)(ws + 5120000);             // 5*16000* 8*4 = 2,560,000 B
  uint32_t* AT   = (uint32_t*)(ws + 8960000);        // 80*640*320*4 = 65,536,000 B (fp16)
  const size_t Goff = 8960000 + 65536000;            // 74,496,000
  const size_t Gb   = (size_t)NIMG * NK * NKP * 4;   // 26,542,080 B (fp16, padded rows)
  // per-phase G buffers if workspace allows (no cross-phase RAW on G);
  // branch depends only on ws_size -> identical work every call (graph-safe)
  size_t Gstride = (ws_size >= Goff + 5 * Gb) ? Gb : 0;

  taps_kernel<<<(NPH * KLEN + 255) / 256, 256, 0, stream>>>(traj, tapw, tapi);
  stageA_kernel<<<NPH * NIMG * 20, 256, 0, stream>>>(img, AT);
  for (int p = 0; p < NPH; p++) {
    uint32_t* Gp = (uint32_t*)(ws + Goff + (size_t)p * Gstride);
    stageB_kernel<<<NIMG * 160, 256, 0, stream>>>(AT, Gp, p);
    interp_kernel<<<2000, 128, 0, stream>>>(Gp, tapw, tapi, out, p);
  }
}

// Round 12
// 292.387 us; speedup vs baseline: 1.2370x; 1.2370x over previous
//
#include <hip/hip_runtime.h>
#include <hip/hip_fp16.h>
#include <cstdint>
#include <cstddef>

// NUFFT type-2, torchkbnufft-compatible (J=6, alpha=14.04, os=2).
// Pipeline (5 phases, 16 coil-images each, 320x320 -> 640x640):
//   taps:   KB weights + [kh_base, 6 wrapped kw indices] per (phase,point)
//   stageA: ALL phases, apodize+pad rows, reg-FFT-640 along W -> AT[pi][kw][h] fp16.
//           256-thread blocks, 16 rows/block, 4 waves x 4 FFTs. LDS stride 709.
//   fused ladder (6 launches), k = 0..5:
//     blocks [0,1000):    interp(phase k-1) — 6x4 uint2 gathers from G[k-1]
//     blocks [1000,3560): stageB(phase k)   — col FFTs -> G[k] (padded rows)
//   stageB (VALU/DS-bound) and interp (latency-bound, VALUBusy ~2%) overlap on
//   complementary pipes; per-phase G buffers make the pair race-free.
//   Both halves keep XCD pinning (image i on XCD i%8; sub-grid offsets %8==0).
// R11 lessons: Tw hoist neutral (compiler already CSE'd); 2 col/wave stageB
// regressed (halved TLP) -> reverted to 1 col/wave, 2560 stageB blocks.
// FFT-640 = four-step 10x64 in registers: zero-padded FFT-10 (2x FFT-5), twiddle,
// 6 __shfl_xor butterfly stages with sign-fold + lane-conditional twiddle.
// fp16 storage: rel err ~5e-4 << 4.06e-2 threshold (measured absmax 0.0078).

#define PI_F     3.14159265358979323846f
#define KB_ALPHA 14.04f
#define NPH  5
#define NIMG 16
#define NH   320
#define NK   640
#define NKP  648   // padded G row stride (uint32 elems); 640..645 mirror 0..5
#define KLEN 16000
#define IBLK 1000  // interp blocks in fused grid (multiple of 8)
#define BBLK 2560  // stageB blocks in fused grid

__device__ __forceinline__ uint32_t f2_to_h2(float2 v) {
  union { __half2 h; uint32_t u; } cv;
  cv.h = __float22half2_rn(v);
  return cv.u;
}
__device__ __forceinline__ float2 h2_to_f2(uint32_t u) {
  union { uint32_t u; __half2 h; } cv;
  cv.u = u;
  return __half22float2(cv.h);
}

// ---- modified Bessel I0 (A&S 9.8.1 / 9.8.2, rel err ~2e-7). I0(alpha) cancels
// between apodization (numerator) and tap weights (denominator). ----
__device__ __forceinline__ float i0f(float x) {
  if (x < 3.75f) {
    float t = x * (1.0f / 3.75f), t2 = t * t;
    return 1.0f + t2 * (3.5156229f + t2 * (3.0899424f + t2 * (1.2067492f +
                 t2 * (0.2659732f + t2 * (0.0360768f + t2 * 0.0045813f)))));
  }
  float t = 3.75f / x;
  float poly = 0.39894228f + t * (0.01328592f + t * (0.00225319f + t * (-0.00157565f +
               t * (0.00916281f + t * (-0.02057706f + t * (0.02635537f +
               t * (-0.01647633f + t * 0.00392377f)))))));
  return expf(x) * rsqrtf(x) * poly;
}

// apodization scale (1/FT(KB)); z^2 = alpha^2-(pi*J*u)^2 > 0 always for |u|<=0.25
__device__ __forceinline__ float apodf(int n) {
  float u = (float)(n - 160) * (1.0f / 640.0f);
  float pj = PI_F * 6.0f * u;
  float z = sqrtf(KB_ALPHA * KB_ALPHA - pj * pj);
  float sh = 0.5f * (expf(z) - expf(-z));     // sinh(z)
  return z * i0f(KB_ALPHA) / (6.0f * sh);     // 1/ft = z*I0a/(J*sinh z)
}

__device__ __forceinline__ float2 cadd(float2 a, float2 b) { return make_float2(a.x + b.x, a.y + b.y); }
__device__ __forceinline__ float2 cmul(float2 a, float2 b) {
  return make_float2(fmaf(a.x, b.x, -a.y * b.y), fmaf(a.x, b.y, a.y * b.x));
}
__device__ __forceinline__ float2 cxmad(float2 a, float2 w, float2 x) {
  a.x = fmaf(w.x, x.x, fmaf(-w.y, x.y, a.x));
  a.y = fmaf(w.x, x.y, fmaf( w.y, x.x, a.y));
  return a;
}

// direct 5-point DFT, forward (W5 = e^{-2pi i/5})
__device__ __forceinline__ void fft5(const float2 b[5], float2 z[5]) {
  const float2 w1 = make_float2( 0.309016994374947424f, -0.951056516295153572f);
  const float2 w2 = make_float2(-0.809016994374947424f, -0.587785252292473129f);
  const float2 w3 = make_float2(-0.809016994374947424f,  0.587785252292473129f);
  const float2 w4 = make_float2( 0.309016994374947424f,  0.951056516295153572f);
  z[0] = cadd(cadd(b[0], b[1]), cadd(cadd(b[2], b[3]), b[4]));
  z[1] = b[0]; z[1] = cxmad(z[1], w1, b[1]); z[1] = cxmad(z[1], w2, b[2]); z[1] = cxmad(z[1], w3, b[3]); z[1] = cxmad(z[1], w4, b[4]);
  z[2] = b[0]; z[2] = cxmad(z[2], w2, b[1]); z[2] = cxmad(z[2], w4, b[2]); z[2] = cxmad(z[2], w1, b[3]); z[2] = cxmad(z[2], w3, b[4]);
  z[3] = b[0]; z[3] = cxmad(z[3], w3, b[1]); z[3] = cxmad(z[3], w1, b[2]); z[3] = cxmad(z[3], w4, b[3]); z[3] = cxmad(z[3], w2, b[4]);
  z[4] = b[0]; z[4] = cxmad(z[4], w4, b[1]); z[4] = cxmad(z[4], w3, b[2]); z[4] = cxmad(z[4], w2, b[3]); z[4] = cxmad(z[4], w1, b[4]);
}

// Register FFT-640 of the zero-padded sequence x[64*n1 + lane] = b[n1] (n1=0..4;
// n1=5..9 implicitly zero). Returns k2 = bitrev6(lane); v[k1] = X[k1 + 10*k2].
__device__ __forceinline__ int fft640_reg(const float2 b[5], float2 v[10], int lane) {
  // FFT-10 with upper half zero: even outputs FFT5(b), odd outputs FFT5(b .* W10^n)
  const float2 t1 = make_float2( 0.809016994374947424f, -0.587785252292473129f); // W10^1
  const float2 t2 = make_float2( 0.309016994374947424f, -0.951056516295153572f); // W10^2
  const float2 t3 = make_float2(-0.309016994374947424f, -0.951056516295153572f); // W10^3
  const float2 t4 = make_float2(-0.809016994374947424f, -0.587785252292473129f); // W10^4
  float2 e[5], o[5], bp[5];
  fft5(b, e);
  bp[0] = b[0]; bp[1] = cmul(b[1], t1); bp[2] = cmul(b[2], t2);
  bp[3] = cmul(b[3], t3); bp[4] = cmul(b[4], t4);
  fft5(bp, o);
  v[0] = e[0]; v[2] = e[1]; v[4] = e[2]; v[6] = e[3]; v[8] = e[4];
  v[1] = o[0]; v[3] = o[1]; v[5] = o[2]; v[7] = o[3]; v[9] = o[4];
  // twiddle: v[k1] *= W640^{lane*k1}
  float sn, cs;
  __sincosf(-2.0f * PI_F * (float)lane * (1.0f / 640.0f), &sn, &cs);
  float2 w1 = make_float2(cs, sn), wk = w1;
  v[1] = cmul(v[1], wk);
#pragma unroll
  for (int k = 2; k < 10; k++) { wk = cmul(wk, w1); v[k] = cmul(v[k], wk); }
  // cross-lane FFT-64 over n2=lane: DIF radix-2, 6 shuffle stages, bitrev output.
#pragma unroll
  for (int s = 5; s >= 1; s--) {
    int half = 1 << s;
    int up = lane & half;
    float ang = -(PI_F / (float)half) * (float)(lane & (half - 1));
    float ss, cc;
    __sincosf(ang, &ss, &cc);
    float sgn = up ? -1.0f : 1.0f;
    float2 twl = make_float2(up ? cc : 1.0f, up ? ss : 0.0f);
#pragma unroll
    for (int q = 0; q < 10; q++) {
      float2 oth;
      oth.x = __shfl_xor(v[q].x, half, 64);
      oth.y = __shfl_xor(v[q].y, half, 64);
      float2 t = make_float2(fmaf(sgn, v[q].x, oth.x), fmaf(sgn, v[q].y, oth.y));
      v[q] = cmul(t, twl);
    }
  }
  {  // final stage half=1: twiddle is identity everywhere — adds/subs only
    float sgn = (lane & 1) ? -1.0f : 1.0f;
#pragma unroll
    for (int q = 0; q < 10; q++) {
      float2 oth;
      oth.x = __shfl_xor(v[q].x, 1, 64);
      oth.y = __shfl_xor(v[q].y, 1, 64);
      v[q] = make_float2(fmaf(sgn, v[q].x, oth.x), fmaf(sgn, v[q].y, oth.y));
    }
  }
  return __brev(lane) >> 26;
}

// ---- stage A: ALL phases. 16 rows/block; 4 waves x 4 sequential row-FFTs,
// fp16 LDS staging (stride 709 >= 703 required by 11*k2+k1 layout),
// transposed write = full 64B lines. grid = 5*16*20 = 1600 blocks x 256 ----
#define ASTR 709
__global__ __launch_bounds__(256) void stageA_kernel(const float* __restrict__ img,
                                                     uint32_t* __restrict__ AT) {
  __shared__ uint32_t lds[16 * ASTR];   // 45,376 B fp16-pairs
  int wv = threadIdx.x >> 6, lane = threadIdx.x & 63;
  int bx = blockIdx.x;
  int p = bx / (NIMG * 20);
  int rem = bx - p * (NIMG * 20);
  int i = rem / 20, hg = rem - i * 20;
  int h0 = hg * 16;
  const float2* base = (const float2*)img + (size_t)(p * NIMG + i) * NH * NH;
  // w-apodization is row-invariant: compute the 5 lane scales once
  float aw[5];
#pragma unroll
  for (int j = 0; j < 5; j++) aw[j] = apodf(lane + 64 * j) * (1.0f / 640.0f);
  // 4 sequential row FFTs per wave: rows r = wv*4 + t
#pragma unroll 1
  for (int t = 0; t < 4; t++) {
    int r = wv * 4 + t;
    int h = h0 + r;
    const float2* src = base + (size_t)h * NH;
    float ah = apodf(h);
    float2 b[5];
#pragma unroll
    for (int j = 0; j < 5; j++) {
      float2 x = src[lane + 64 * j];
      float sc = aw[j] * ah;
      b[j] = make_float2(x.x * sc, x.y * sc);
    }
    float2 v[10];
    int k2 = fft640_reg(b, v, lane);
    uint32_t* rowl = lds + r * ASTR + 11 * k2;   // kw=k1+10*k2 at 11*k2+k1 (max 702 < 709)
#pragma unroll
    for (int k = 0; k < 10; k++) rowl[k] = f2_to_h2(v[k]);
  }
  __syncthreads();
  // transposed write: AT[kw][h0+c], c = tid&15 -> 16 consecutive h = 64B line
  int c = threadIdx.x & 15, kwv = threadIdx.x >> 4;   // kwv in [0,16)
  uint32_t* dst = AT + (size_t)(p * NIMG + i) * NK * NH + h0 + c;
  const uint32_t* srcl = lds + c * ASTR;
#pragma unroll
  for (int s = 0; s < 40; s++) {
    int kw = kwv + 16 * s;
    int q2 = (kw * 6554) >> 16;     // kw/10 (exact for kw<1638)
    int q1 = kw - 10 * q2;
    dst[(size_t)kw * NH] = srcl[11 * q2 + q1];
  }
}

// ---- taps: per (phase, point): kh weights[6], kw weights[6], phase (c,s) in tapw
// (stride 16 floats); [kh_base, kw_idx[6], pad] in tapi (stride 8 ints, int4x2) ----
__global__ __launch_bounds__(256) void taps_kernel(const float* __restrict__ traj,
                                                   float* __restrict__ tapw,
                                                   int* __restrict__ tapi) {
  int t = blockIdx.x * 256 + threadIdx.x;
  if (t >= NPH * KLEN) return;
  int p = t / KLEN, l = t - p * KLEN;
  float inv_i0a = 1.0f / i0f(KB_ALPHA);
  float* wout = tapw + (size_t)t * 16;
  int* iout = tapi + (size_t)t * 8;
  float ang = 0.0f;
#pragma unroll
  for (int d = 0; d < 2; d++) {
    float om = traj[((size_t)p * 2 + d) * KLEN + l];
    float tt = om * 640.0f / 6.28318530717958647692f;
    float base = floorf(tt - 3.0f);
    ang += om * 160.0f;              // n_shift = 320//2
    if (d == 0) {                    // kh: store base index only (taps consecutive)
      int bi = (int)base + 1 + 640;  // [318, 958]
      if (bi >= 640) bi -= 640;      // [0, 639]
      iout[0] = bi;
    }
#pragma unroll
    for (int j = 0; j < 6; j++) {
      float kf = base + (float)(j + 1);
      float u = tt - kf;
      float arg = fmaxf(1.0f - (u * u) * (1.0f / 9.0f), 0.0f);
      wout[d * 6 + j] = i0f(KB_ALPHA * sqrtf(arg)) * inv_i0a;
      if (d == 1) {                  // kw: individually wrapped indices
        int ki = (int)kf + 640;
        if (ki >= 640) ki -= 640;
        iout[1 + j] = ki;
      }
    }
  }
  float s, c;
  sincosf(ang, &s, &c);              // accurate path: |ang| up to ~1005 rad
  wout[12] = c;
  wout[13] = s;
  wout[14] = 0.f;
  wout[15] = 0.f;
  iout[7] = 0;
}

// ---- fused ladder kernel: blocks [0,IBLK) = interp(pi) from Gr;
// blocks [IBLK,IBLK+BBLK) = stageB(pb) into Gw. pi<0 / pb>=NPH disable a half.
// Both halves XCD-pinned (image i on XCD i%8; both sub-grid offsets %8==0). ----
__global__ __launch_bounds__(256) void fusedBI_kernel(
    const uint32_t* __restrict__ AT, uint32_t* __restrict__ Gw,
    const uint32_t* __restrict__ Gr, const float* __restrict__ tapw,
    const int* __restrict__ tapi, float* __restrict__ out, int pb, int pi) {
  if (blockIdx.x < IBLK) {
    // ---------------- interp half ----------------
    if (pi < 0) return;
    int bx = blockIdx.x;
    int x = bx & 7;                        // XCD
    int q = ((bx >> 3) << 8) + threadIdx.x;   // 0..31999 within XCD pair
    int over = (q >= KLEN) ? 1 : 0;
    int i = x + 8 * over;
    int l = q - KLEN * over;
    const float4* w4 = (const float4*)(tapw + (size_t)(pi * KLEN + l) * 16);
    float4 wa = w4[0], wb = w4[1], wc = w4[2], wd = w4[3];
    const int4* i4 = (const int4*)(tapi + (size_t)(pi * KLEN + l) * 8);
    int4 ia = i4[0], ib = i4[1];
    float whv[6] = {wa.x, wa.y, wa.z, wa.w, wb.x, wb.y};
    float wwv[6] = {wb.z, wb.w, wc.x, wc.y, wc.z, wc.w};
    int   iwv[6] = {ia.y, ia.z, ia.w, ib.x, ib.y, ib.z};
    int   b0 = ia.x;
    int   e = b0 & ~1, off = b0 & 1;
    // 7-wide shifted kh-weight window (off=0: w0..w5 at 0..5; off=1: at 1..6)
    float we[7];
    we[0] = off ? 0.f    : whv[0];
    we[1] = off ? whv[0] : whv[1];
    we[2] = off ? whv[1] : whv[2];
    we[3] = off ? whv[2] : whv[3];
    we[4] = off ? whv[3] : whv[4];
    we[5] = off ? whv[4] : whv[5];
    we[6] = off ? whv[5] : 0.f;
    const uint32_t* g = Gr + (size_t)i * (NK * NKP) + e;
    uint2 raw[6][4];
#pragma unroll
    for (int jw = 0; jw < 6; jw++) {
      const uint2* col = (const uint2*)(g + iwv[jw] * NKP);
#pragma unroll
      for (int m = 0; m < 4; m++) raw[jw][m] = col[m];
    }
    __builtin_amdgcn_sched_barrier(0);   // don't sink loads into the FMA chain
    float ar = 0.f, ai = 0.f;
#pragma unroll
    for (int jw = 0; jw < 6; jw++) {
      float sr = 0.f, si = 0.f;
#pragma unroll
      for (int k = 0; k < 7; k++) {
        uint32_t u = (k & 1) ? raw[jw][k >> 1].y : raw[jw][k >> 1].x;
        float2 v = h2_to_f2(u);
        sr = fmaf(we[k], v.x, sr);
        si = fmaf(we[k], v.y, si);
      }
      ar = fmaf(wwv[jw], sr, ar);
      ai = fmaf(wwv[jw], si, ai);
    }
    float c = wd.x, s = wd.y;
    size_t o = (size_t)(pi * NIMG + i) * KLEN + l;
    ((float2*)out)[o] = make_float2(ar * c - ai * s, ar * s + ai * c);
  } else {
    // ---------------- stageB half (1 col/wave, R10-proven) ----------------
    if (pb >= NPH) return;
    int bx = blockIdx.x - IBLK;
    int wv = threadIdx.x >> 6, lane = threadIdx.x & 63;
    int x = bx & 7;
    int J = bx >> 3;                 // 0..319
    int i = x + 8 * (J >= 160);
    int kwg = (J >= 160) ? J - 160 : J;
    int kw = kwg * 4 + wv;
    const uint32_t* rowp = AT + ((size_t)(pb * NIMG + i) * NK + kw) * NH;  // contiguous
    float2 b[5];
#pragma unroll
    for (int j = 0; j < 5; j++) b[j] = h2_to_f2(rowp[lane + 64 * j]);
    float2 v[10];
    int k2 = fft640_reg(b, v, lane);
    uint32_t hv[10];
#pragma unroll
    for (int k = 0; k < 10; k++) hv[k] = f2_to_h2(v[k]);
    uint32_t* rowo = Gw + ((size_t)i * NK + kw) * NKP;
    uint2* dst = (uint2*)(rowo + 10 * k2);
#pragma unroll
    for (int m = 0; m < 5; m++) dst[m] = make_uint2(hv[2 * m], hv[2 * m + 1]);
    if (k2 == 0) {                   // mirror kh 0..5 at 640..645 (no wrap in interp)
      uint2* pd = (uint2*)(rowo + 640);
#pragma unroll
      for (int m = 0; m < 3; m++) pd[m] = make_uint2(hv[2 * m], hv[2 * m + 1]);
    }
  }
}

extern "C" void kernel_launch(void* const* d_in, const int* in_sizes, int n_in,
                              void* d_out, int out_size, void* d_ws, size_t ws_size,
                              hipStream_t stream) {
  const float* img  = (const float*)d_in[0];   // (1,5,8,2,320,320,2) f32
  const float* traj = (const float*)d_in[1];   // (5,2,16000) f32
  float* out = (float*)d_out;                  // (1,5,8,2,16000,2) f32

  char* ws = (char*)d_ws;
  float*    tapw = (float*)ws;                       // 5*16000*16*4 = 5,120,000 B
  int*      tapi = (int*)(ws + 5120000);             // 5*16000* 8*4 = 2,560,000 B
  uint32_t* AT   = (uint32_t*)(ws + 8960000);        // 80*640*320*4 = 65,536,000 B (fp16)
  const size_t Goff = 8960000 + 65536000;            // 74,496,000
  const size_t Gb   = (size_t)NIMG * NK * NKP * 4;   // 26,542,080 B (fp16, padded rows)
  // per-phase G buffers (needed by the fused ladder). Branch depends only on
  // ws_size -> identical work every call (graph-safe). Total need: ~207 MB.
  bool has5 = (ws_size >= Goff + 5 * Gb);

  taps_kernel<<<(NPH * KLEN + 255) / 256, 256, 0, stream>>>(traj, tapw, tapi);
  stageA_kernel<<<NPH * NIMG * 20, 256, 0, stream>>>(img, AT);
  if (has5) {
    // ladder: launch k does stageB(k) + interp(k-1) concurrently
    for (int k = 0; k <= NPH; k++) {
      uint32_t* Gw = (uint32_t*)(ws + Goff + (size_t)((k < NPH) ? k : 0) * Gb);
      uint32_t* Gr = (uint32_t*)(ws + Goff + (size_t)((k > 0) ? k - 1 : 0) * Gb);
      fusedBI_kernel<<<IBLK + BBLK, 256, 0, stream>>>(AT, Gw, Gr, tapw, tapi, out,
                                                      k, k - 1);
    }
  } else {
    // fallback: single G buffer, strictly sequential B then I per phase
    uint32_t* G0 = (uint32_t*)(ws + Goff);
    for (int p = 0; p < NPH; p++) {
      fusedBI_kernel<<<IBLK + BBLK, 256, 0, stream>>>(AT, G0, G0, tapw, tapi, out,
                                                      p, -1);
      fusedBI_kernel<<<IBLK + BBLK, 256, 0, stream>>>(AT, G0, G0, tapw, tapi, out,
                                                      NPH, p);
    }
  }
}

// Round 13
// 290.144 us; speedup vs baseline: 1.2465x; 1.0077x over previous
//
#include <hip/hip_runtime.h>
#include <hip/hip_fp16.h>
#include <cstdint>
#include <cstddef>

// NUFFT type-2, torchkbnufft-compatible (J=6, alpha=14.04, os=2).
// Pipeline (5 phases, 16 coil-images each, 320x320 -> 640x640):
//   taps:   KB weights + [kh_base, 6 wrapped kw indices] per (phase,point)
//   stageA: ALL phases, apodize+pad rows, reg-FFT-640 along W -> AT[pi][kw][h] fp16.
//           256-thread blocks, 16 rows/block, 4 waves x 2 iterations of an
//           INTERLEAVED 2-FFT chain (R12 diagnosis: stageA is dependency-
//           latency-bound at 1.8 waves/SIMD — one serial shuffle chain per wave
//           can't fill either pipe; 2 independent FFTs double per-wave ILP).
//           LDS stride 709 (>=703 needed by 11*k2+k1 layout).
//   fused ladder (6 launches), k = 0..5:
//     blocks [0,1000):    interp(phase k-1) — 6x4 uint2 gathers from G[k-1]
//     blocks [1000,3560): stageB(phase k)   — col FFTs -> G[k] (padded rows)
//   Both halves XCD-pinned (image i on XCD i%8; sub-grid offsets %8==0).
// FFT-640 = four-step 10x64 in registers: zero-padded FFT-10 (2x FFT-5), twiddle,
// 6 __shfl_xor butterfly stages with sign-fold + lane-conditional twiddle.
// fp16 storage: rel err ~5e-4 << 4.06e-2 threshold (measured absmax 0.0078).

#define PI_F     3.14159265358979323846f
#define KB_ALPHA 14.04f
#define NPH  5
#define NIMG 16
#define NH   320
#define NK   640
#define NKP  648   // padded G row stride (uint32 elems); 640..645 mirror 0..5
#define KLEN 16000
#define IBLK 1000  // interp blocks in fused grid (multiple of 8)
#define BBLK 2560  // stageB blocks in fused grid

__device__ __forceinline__ uint32_t f2_to_h2(float2 v) {
  union { __half2 h; uint32_t u; } cv;
  cv.h = __float22half2_rn(v);
  return cv.u;
}
__device__ __forceinline__ float2 h2_to_f2(uint32_t u) {
  union { uint32_t u; __half2 h; } cv;
  cv.u = u;
  return __half22float2(cv.h);
}

// ---- modified Bessel I0 (A&S 9.8.1 / 9.8.2, rel err ~2e-7). I0(alpha) cancels
// between apodization (numerator) and tap weights (denominator). ----
__device__ __forceinline__ float i0f(float x) {
  if (x < 3.75f) {
    float t = x * (1.0f / 3.75f), t2 = t * t;
    return 1.0f + t2 * (3.5156229f + t2 * (3.0899424f + t2 * (1.2067492f +
                 t2 * (0.2659732f + t2 * (0.0360768f + t2 * 0.0045813f)))));
  }
  float t = 3.75f / x;
  float poly = 0.39894228f + t * (0.01328592f + t * (0.00225319f + t * (-0.00157565f +
               t * (0.00916281f + t * (-0.02057706f + t * (0.02635537f +
               t * (-0.01647633f + t * 0.00392377f)))))));
  return expf(x) * rsqrtf(x) * poly;
}

// apodization scale (1/FT(KB)); z^2 = alpha^2-(pi*J*u)^2 > 0 always for |u|<=0.25
__device__ __forceinline__ float apodf(int n) {
  float u = (float)(n - 160) * (1.0f / 640.0f);
  float pj = PI_F * 6.0f * u;
  float z = sqrtf(KB_ALPHA * KB_ALPHA - pj * pj);
  float sh = 0.5f * (expf(z) - expf(-z));     // sinh(z)
  return z * i0f(KB_ALPHA) / (6.0f * sh);     // 1/ft = z*I0a/(J*sinh z)
}

__device__ __forceinline__ float2 cadd(float2 a, float2 b) { return make_float2(a.x + b.x, a.y + b.y); }
__device__ __forceinline__ float2 cmul(float2 a, float2 b) {
  return make_float2(fmaf(a.x, b.x, -a.y * b.y), fmaf(a.x, b.y, a.y * b.x));
}
__device__ __forceinline__ float2 cxmad(float2 a, float2 w, float2 x) {
  a.x = fmaf(w.x, x.x, fmaf(-w.y, x.y, a.x));
  a.y = fmaf(w.x, x.y, fmaf( w.y, x.x, a.y));
  return a;
}

// direct 5-point DFT, forward (W5 = e^{-2pi i/5})
__device__ __forceinline__ void fft5(const float2 b[5], float2 z[5]) {
  const float2 w1 = make_float2( 0.309016994374947424f, -0.951056516295153572f);
  const float2 w2 = make_float2(-0.809016994374947424f, -0.587785252292473129f);
  const float2 w3 = make_float2(-0.809016994374947424f,  0.587785252292473129f);
  const float2 w4 = make_float2( 0.309016994374947424f,  0.951056516295153572f);
  z[0] = cadd(cadd(b[0], b[1]), cadd(cadd(b[2], b[3]), b[4]));
  z[1] = b[0]; z[1] = cxmad(z[1], w1, b[1]); z[1] = cxmad(z[1], w2, b[2]); z[1] = cxmad(z[1], w3, b[3]); z[1] = cxmad(z[1], w4, b[4]);
  z[2] = b[0]; z[2] = cxmad(z[2], w2, b[1]); z[2] = cxmad(z[2], w4, b[2]); z[2] = cxmad(z[2], w1, b[3]); z[2] = cxmad(z[2], w3, b[4]);
  z[3] = b[0]; z[3] = cxmad(z[3], w3, b[1]); z[3] = cxmad(z[3], w1, b[2]); z[3] = cxmad(z[3], w4, b[3]); z[3] = cxmad(z[3], w2, b[4]);
  z[4] = b[0]; z[4] = cxmad(z[4], w4, b[1]); z[4] = cxmad(z[4], w3, b[2]); z[4] = cxmad(z[4], w2, b[3]); z[4] = cxmad(z[4], w1, b[4]);
}

// NF interleaved register FFT-640s of zero-padded sequences (n1=0..4 live).
// Independent chains interleaved at every stage -> NF x per-wave ILP.
// Returns k2 = bitrev6(lane); v[f][k1] = X_f[k1 + 10*k2].
template <int NF>
__device__ __forceinline__ int fft640_regN(const float2 b[NF][5], float2 v[NF][10],
                                           int lane) {
  const float2 t1 = make_float2( 0.809016994374947424f, -0.587785252292473129f); // W10^1
  const float2 t2 = make_float2( 0.309016994374947424f, -0.951056516295153572f); // W10^2
  const float2 t3 = make_float2(-0.309016994374947424f, -0.951056516295153572f); // W10^3
  const float2 t4 = make_float2(-0.809016994374947424f, -0.587785252292473129f); // W10^4
#pragma unroll
  for (int f = 0; f < NF; f++) {
    float2 e[5], o[5], bp[5];
    fft5(b[f], e);
    bp[0] = b[f][0]; bp[1] = cmul(b[f][1], t1); bp[2] = cmul(b[f][2], t2);
    bp[3] = cmul(b[f][3], t3); bp[4] = cmul(b[f][4], t4);
    fft5(bp, o);
    v[f][0] = e[0]; v[f][2] = e[1]; v[f][4] = e[2]; v[f][6] = e[3]; v[f][8] = e[4];
    v[f][1] = o[0]; v[f][3] = o[1]; v[f][5] = o[2]; v[f][7] = o[3]; v[f][9] = o[4];
  }
  // twiddle: v[f][k1] *= W640^{lane*k1}
  float sn, cs;
  __sincosf(-2.0f * PI_F * (float)lane * (1.0f / 640.0f), &sn, &cs);
  float2 w1 = make_float2(cs, sn), wk = w1;
#pragma unroll
  for (int k = 1; k < 10; k++) {
#pragma unroll
    for (int f = 0; f < NF; f++) v[f][k] = cmul(v[f][k], wk);
    if (k < 9) wk = cmul(wk, w1);
  }
  // cross-lane FFT-64 over n2=lane: DIF radix-2, 6 shuffle stages, bitrev output.
#pragma unroll
  for (int s = 5; s >= 1; s--) {
    int half = 1 << s;
    int up = lane & half;
    float ang = -(PI_F / (float)half) * (float)(lane & (half - 1));
    float ss, cc;
    __sincosf(ang, &ss, &cc);
    float sgn = up ? -1.0f : 1.0f;
    float2 twl = make_float2(up ? cc : 1.0f, up ? ss : 0.0f);
#pragma unroll
    for (int f = 0; f < NF; f++)
#pragma unroll
      for (int q = 0; q < 10; q++) {
        float2 oth;
        oth.x = __shfl_xor(v[f][q].x, half, 64);
        oth.y = __shfl_xor(v[f][q].y, half, 64);
        float2 t = make_float2(fmaf(sgn, v[f][q].x, oth.x), fmaf(sgn, v[f][q].y, oth.y));
        v[f][q] = cmul(t, twl);
      }
  }
  {  // final stage half=1: twiddle is identity everywhere — adds/subs only
    float sgn = (lane & 1) ? -1.0f : 1.0f;
#pragma unroll
    for (int f = 0; f < NF; f++)
#pragma unroll
      for (int q = 0; q < 10; q++) {
        float2 oth;
        oth.x = __shfl_xor(v[f][q].x, 1, 64);
        oth.y = __shfl_xor(v[f][q].y, 1, 64);
        v[f][q] = make_float2(fmaf(sgn, v[f][q].x, oth.x), fmaf(sgn, v[f][q].y, oth.y));
      }
  }
  return __brev(lane) >> 26;
}

// ---- stage A: ALL phases. 16 rows/block; 4 waves x 2 iterations x 2 interleaved
// FFTs, fp16 LDS staging (stride 709 >= 703 required by 11*k2+k1 layout),
// transposed write = full 64B lines. grid = 5*16*20 = 1600 blocks x 256 ----
#define ASTR 709
__global__ __launch_bounds__(256) void stageA_kernel(const float* __restrict__ img,
                                                     uint32_t* __restrict__ AT) {
  __shared__ uint32_t lds[16 * ASTR];   // 45,376 B fp16-pairs
  int wv = threadIdx.x >> 6, lane = threadIdx.x & 63;
  int bx = blockIdx.x;
  int p = bx / (NIMG * 20);
  int rem = bx - p * (NIMG * 20);
  int i = rem / 20, hg = rem - i * 20;
  int h0 = hg * 16;
  const float2* base = (const float2*)img + (size_t)(p * NIMG + i) * NH * NH;
  // w-apodization is row-invariant: compute the 5 lane scales once
  float aw[5];
#pragma unroll
  for (int j = 0; j < 5; j++) aw[j] = apodf(lane + 64 * j) * (1.0f / 640.0f);
  // 2 iterations x 2 interleaved row FFTs per wave: rows r = wv*4 + 2t + {0,1}
#pragma unroll 1
  for (int t = 0; t < 2; t++) {
    int r0 = wv * 4 + 2 * t;
    float2 b[2][5];
#pragma unroll
    for (int f = 0; f < 2; f++) {
      int h = h0 + r0 + f;
      const float2* src = base + (size_t)h * NH;
      float ah = apodf(h);
#pragma unroll
      for (int j = 0; j < 5; j++) {
        float2 x = src[lane + 64 * j];
        float sc = aw[j] * ah;
        b[f][j] = make_float2(x.x * sc, x.y * sc);
      }
    }
    float2 v[2][10];
    int k2 = fft640_regN<2>(b, v, lane);
#pragma unroll
    for (int f = 0; f < 2; f++) {
      uint32_t* rowl = lds + (r0 + f) * ASTR + 11 * k2;  // max 702 < 709
#pragma unroll
      for (int k = 0; k < 10; k++) rowl[k] = f2_to_h2(v[f][k]);
    }
  }
  __syncthreads();
  // transposed write: AT[kw][h0+c], c = tid&15 -> 16 consecutive h = 64B line
  int c = threadIdx.x & 15, kwv = threadIdx.x >> 4;   // kwv in [0,16)
  uint32_t* dst = AT + (size_t)(p * NIMG + i) * NK * NH + h0 + c;
  const uint32_t* srcl = lds + c * ASTR;
#pragma unroll
  for (int s = 0; s < 40; s++) {
    int kw = kwv + 16 * s;
    int q2 = (kw * 6554) >> 16;     // kw/10 (exact for kw<1638)
    int q1 = kw - 10 * q2;
    dst[(size_t)kw * NH] = srcl[11 * q2 + q1];
  }
}

// ---- taps: per (phase, point): kh weights[6], kw weights[6], phase (c,s) in tapw
// (stride 16 floats); [kh_base, kw_idx[6], pad] in tapi (stride 8 ints, int4x2) ----
__global__ __launch_bounds__(256) void taps_kernel(const float* __restrict__ traj,
                                                   float* __restrict__ tapw,
                                                   int* __restrict__ tapi) {
  int t = blockIdx.x * 256 + threadIdx.x;
  if (t >= NPH * KLEN) return;
  int p = t / KLEN, l = t - p * KLEN;
  float inv_i0a = 1.0f / i0f(KB_ALPHA);
  float* wout = tapw + (size_t)t * 16;
  int* iout = tapi + (size_t)t * 8;
  float ang = 0.0f;
#pragma unroll
  for (int d = 0; d < 2; d++) {
    float om = traj[((size_t)p * 2 + d) * KLEN + l];
    float tt = om * 640.0f / 6.28318530717958647692f;
    float base = floorf(tt - 3.0f);
    ang += om * 160.0f;              // n_shift = 320//2
    if (d == 0) {                    // kh: store base index only (taps consecutive)
      int bi = (int)base + 1 + 640;  // [318, 958]
      if (bi >= 640) bi -= 640;      // [0, 639]
      iout[0] = bi;
    }
#pragma unroll
    for (int j = 0; j < 6; j++) {
      float kf = base + (float)(j + 1);
      float u = tt - kf;
      float arg = fmaxf(1.0f - (u * u) * (1.0f / 9.0f), 0.0f);
      wout[d * 6 + j] = i0f(KB_ALPHA * sqrtf(arg)) * inv_i0a;
      if (d == 1) {                  // kw: individually wrapped indices
        int ki = (int)kf + 640;
        if (ki >= 640) ki -= 640;
        iout[1 + j] = ki;
      }
    }
  }
  float s, c;
  sincosf(ang, &s, &c);              // accurate path: |ang| up to ~1005 rad
  wout[12] = c;
  wout[13] = s;
  wout[14] = 0.f;
  wout[15] = 0.f;
  iout[7] = 0;
}

// ---- fused ladder kernel: blocks [0,IBLK) = interp(pi) from Gr;
// blocks [IBLK,IBLK+BBLK) = stageB(pb) into Gw. pi<0 / pb>=NPH disable a half.
// Both halves XCD-pinned (image i on XCD i%8; both sub-grid offsets %8==0). ----
__global__ __launch_bounds__(256) void fusedBI_kernel(
    const uint32_t* __restrict__ AT, uint32_t* __restrict__ Gw,
    const uint32_t* __restrict__ Gr, const float* __restrict__ tapw,
    const int* __restrict__ tapi, float* __restrict__ out, int pb, int pi) {
  if (blockIdx.x < IBLK) {
    // ---------------- interp half ----------------
    if (pi < 0) return;
    int bx = blockIdx.x;
    int x = bx & 7;                        // XCD
    int q = ((bx >> 3) << 8) + threadIdx.x;   // 0..31999 within XCD pair
    int over = (q >= KLEN) ? 1 : 0;
    int i = x + 8 * over;
    int l = q - KLEN * over;
    const float4* w4 = (const float4*)(tapw + (size_t)(pi * KLEN + l) * 16);
    float4 wa = w4[0], wb = w4[1], wc = w4[2], wd = w4[3];
    const int4* i4 = (const int4*)(tapi + (size_t)(pi * KLEN + l) * 8);
    int4 ia = i4[0], ib = i4[1];
    float whv[6] = {wa.x, wa.y, wa.z, wa.w, wb.x, wb.y};
    float wwv[6] = {wb.z, wb.w, wc.x, wc.y, wc.z, wc.w};
    int   iwv[6] = {ia.y, ia.z, ia.w, ib.x, ib.y, ib.z};
    int   b0 = ia.x;
    int   e = b0 & ~1, off = b0 & 1;
    // 7-wide shifted kh-weight window (off=0: w0..w5 at 0..5; off=1: at 1..6)
    float we[7];
    we[0] = off ? 0.f    : whv[0];
    we[1] = off ? whv[0] : whv[1];
    we[2] = off ? whv[1] : whv[2];
    we[3] = off ? whv[2] : whv[3];
    we[4] = off ? whv[3] : whv[4];
    we[5] = off ? whv[4] : whv[5];
    we[6] = off ? whv[5] : 0.f;
    const uint32_t* g = Gr + (size_t)i * (NK * NKP) + e;
    uint2 raw[6][4];
#pragma unroll
    for (int jw = 0; jw < 6; jw++) {
      const uint2* col = (const uint2*)(g + iwv[jw] * NKP);
#pragma unroll
      for (int m = 0; m < 4; m++) raw[jw][m] = col[m];
    }
    __builtin_amdgcn_sched_barrier(0);   // don't sink loads into the FMA chain
    float ar = 0.f, ai = 0.f;
#pragma unroll
    for (int jw = 0; jw < 6; jw++) {
      float sr = 0.f, si = 0.f;
#pragma unroll
      for (int k = 0; k < 7; k++) {
        uint32_t u = (k & 1) ? raw[jw][k >> 1].y : raw[jw][k >> 1].x;
        float2 v = h2_to_f2(u);
        sr = fmaf(we[k], v.x, sr);
        si = fmaf(we[k], v.y, si);
      }
      ar = fmaf(wwv[jw], sr, ar);
      ai = fmaf(wwv[jw], si, ai);
    }
    float c = wd.x, s = wd.y;
    size_t o = (size_t)(pi * NIMG + i) * KLEN + l;
    ((float2*)out)[o] = make_float2(ar * c - ai * s, ar * s + ai * c);
  } else {
    // ---------------- stageB half (1 col/wave, R10-proven) ----------------
    if (pb >= NPH) return;
    int bx = blockIdx.x - IBLK;
    int wv = threadIdx.x >> 6, lane = threadIdx.x & 63;
    int x = bx & 7;
    int J = bx >> 3;                 // 0..319
    int i = x + 8 * (J >= 160);
    int kwg = (J >= 160) ? J - 160 : J;
    int kw = kwg * 4 + wv;
    const uint32_t* rowp = AT + ((size_t)(pb * NIMG + i) * NK + kw) * NH;  // contiguous
    float2 b[1][5];
#pragma unroll
    for (int j = 0; j < 5; j++) b[0][j] = h2_to_f2(rowp[lane + 64 * j]);
    float2 v[1][10];
    int k2 = fft640_regN<1>(b, v, lane);
    uint32_t hv[10];
#pragma unroll
    for (int k = 0; k < 10; k++) hv[k] = f2_to_h2(v[0][k]);
    uint32_t* rowo = Gw + ((size_t)i * NK + kw) * NKP;
    uint2* dst = (uint2*)(rowo + 10 * k2);
#pragma unroll
    for (int m = 0; m < 5; m++) dst[m] = make_uint2(hv[2 * m], hv[2 * m + 1]);
    if (k2 == 0) {                   // mirror kh 0..5 at 640..645 (no wrap in interp)
      uint2* pd = (uint2*)(rowo + 640);
#pragma unroll
      for (int m = 0; m < 3; m++) pd[m] = make_uint2(hv[2 * m], hv[2 * m + 1]);
    }
  }
}

extern "C" void kernel_launch(void* const* d_in, const int* in_sizes, int n_in,
                              void* d_out, int out_size, void* d_ws, size_t ws_size,
                              hipStream_t stream) {
  const float* img  = (const float*)d_in[0];   // (1,5,8,2,320,320,2) f32
  const float* traj = (const float*)d_in[1];   // (5,2,16000) f32
  float* out = (float*)d_out;                  // (1,5,8,2,16000,2) f32

  char* ws = (char*)d_ws;
  float*    tapw = (float*)ws;                       // 5*16000*16*4 = 5,120,000 B
  int*      tapi = (int*)(ws + 5120000);             // 5*16000* 8*4 = 2,560,000 B
  uint32_t* AT   = (uint32_t*)(ws + 8960000);        // 80*640*320*4 = 65,536,000 B (fp16)
  const size_t Goff = 8960000 + 65536000;            // 74,496,000
  const size_t Gb   = (size_t)NIMG * NK * NKP * 4;   // 26,542,080 B (fp16, padded rows)
  // per-phase G buffers (needed by the fused ladder). Branch depends only on
  // ws_size -> identical work every call (graph-safe). Total need: ~207 MB.
  bool has5 = (ws_size >= Goff + 5 * Gb);

  taps_kernel<<<(NPH * KLEN + 255) / 256, 256, 0, stream>>>(traj, tapw, tapi);
  stageA_kernel<<<NPH * NIMG * 20, 256, 0, stream>>>(img, AT);
  if (has5) {
    // ladder: launch k does stageB(k) + interp(k-1) concurrently
    for (int k = 0; k <= NPH; k++) {
      uint32_t* Gw = (uint32_t*)(ws + Goff + (size_t)((k < NPH) ? k : 0) * Gb);
      uint32_t* Gr = (uint32_t*)(ws + Goff + (size_t)((k > 0) ? k - 1 : 0) * Gb);
      fusedBI_kernel<<<IBLK + BBLK, 256, 0, stream>>>(AT, Gw, Gr, tapw, tapi, out,
                                                      k, k - 1);
    }
  } else {
    // fallback: single G buffer, strictly sequential B then I per phase
    uint32_t* G0 = (uint32_t*)(ws + Goff);
    for (int p = 0; p < NPH; p++) {
      fusedBI_kernel<<<IBLK + BBLK, 256, 0, stream>>>(AT, G0, G0, tapw, tapi, out,
                                                      p, -1);
      fusedBI_kernel<<<IBLK + BBLK, 256, 0, stream>>>(AT, G0, G0, tapw, tapi, out,
                                                      NPH, p);
    }
  }
}

// Round 14
// 287.064 us; speedup vs baseline: 1.2599x; 1.0107x over previous
//
#include <hip/hip_runtime.h>
#include <hip/hip_fp16.h>
#include <cstdint>
#include <cstddef>

// NUFFT type-2, torchkbnufft-compatible (J=6, alpha=14.04, os=2).
// Pipeline (5 phases, 16 coil-images each, 320x320 -> 640x640):
//   taps:   KB weights + [kh_base, 6 wrapped kw indices] per (phase,point)
//   stageA: ALL phases, apodize+pad rows, reg-FFT-640 along W -> AT[pi][kw][h] fp16.
//           256t blocks, 16 rows/block, 4 waves x 2 iter x 2 interleaved FFTs.
//           LDS stride 709 (>=703 needed by 11*k2+k1 layout).
//   HALF-PHASE fused ladder (11 launches), step s = 0..10 (phase s>>1, half s&1):
//     blocks [0,1280):     stageB(step s)   — col FFTs of 8 images (1/XCD) -> G
//     blocks [1280,1784):  interp(step s-1) — 6x4 uint2 gathers, 8 images (1/XCD)
//   Per-XCD working set: Gw 1.68 + Gr 1.68 + AT 0.82 = 4.2MB ~ L2 (R13's full
//   phases pushed 8.4MB/XCD -> G evicted, fusion ran at sum not max).
//   Race-free: odd steps write half1 while interp reads half0 of the same phase
//   buffer (disjoint images); even steps touch different phase buffers.
// FFT-640 = four-step 10x64 in registers: zero-padded FFT-10 (2x FFT-5), twiddle,
// 6 __shfl_xor butterfly stages with sign-fold + lane-conditional twiddle.
// fp16 storage: rel err ~5e-4 << 4.06e-2 threshold (measured absmax 0.0078).

#define PI_F     3.14159265358979323846f
#define KB_ALPHA 14.04f
#define NPH  5
#define NIMG 16
#define NH   320
#define NK   640
#define NKP  648   // padded G row stride (uint32 elems); 640..645 mirror 0..5
#define KLEN 16000
#define BBLK2 1280  // stageB blocks (8 images, 160/XCD)
#define IBLK2 504   // interp blocks (63/XCD x 256 thr = 16128 >= 16000)

__device__ __forceinline__ uint32_t f2_to_h2(float2 v) {
  union { __half2 h; uint32_t u; } cv;
  cv.h = __float22half2_rn(v);
  return cv.u;
}
__device__ __forceinline__ float2 h2_to_f2(uint32_t u) {
  union { uint32_t u; __half2 h; } cv;
  cv.u = u;
  return __half22float2(cv.h);
}

// ---- modified Bessel I0 (A&S 9.8.1 / 9.8.2, rel err ~2e-7). I0(alpha) cancels
// between apodization (numerator) and tap weights (denominator). ----
__device__ __forceinline__ float i0f(float x) {
  if (x < 3.75f) {
    float t = x * (1.0f / 3.75f), t2 = t * t;
    return 1.0f + t2 * (3.5156229f + t2 * (3.0899424f + t2 * (1.2067492f +
                 t2 * (0.2659732f + t2 * (0.0360768f + t2 * 0.0045813f)))));
  }
  float t = 3.75f / x;
  float poly = 0.39894228f + t * (0.01328592f + t * (0.00225319f + t * (-0.00157565f +
               t * (0.00916281f + t * (-0.02057706f + t * (0.02635537f +
               t * (-0.01647633f + t * 0.00392377f)))))));
  return expf(x) * rsqrtf(x) * poly;
}

// apodization scale (1/FT(KB)); z^2 = alpha^2-(pi*J*u)^2 > 0 always for |u|<=0.25
__device__ __forceinline__ float apodf(int n) {
  float u = (float)(n - 160) * (1.0f / 640.0f);
  float pj = PI_F * 6.0f * u;
  float z = sqrtf(KB_ALPHA * KB_ALPHA - pj * pj);
  float sh = 0.5f * (expf(z) - expf(-z));     // sinh(z)
  return z * i0f(KB_ALPHA) / (6.0f * sh);     // 1/ft = z*I0a/(J*sinh z)
}

__device__ __forceinline__ float2 cadd(float2 a, float2 b) { return make_float2(a.x + b.x, a.y + b.y); }
__device__ __forceinline__ float2 cmul(float2 a, float2 b) {
  return make_float2(fmaf(a.x, b.x, -a.y * b.y), fmaf(a.x, b.y, a.y * b.x));
}
__device__ __forceinline__ float2 cxmad(float2 a, float2 w, float2 x) {
  a.x = fmaf(w.x, x.x, fmaf(-w.y, x.y, a.x));
  a.y = fmaf(w.x, x.y, fmaf( w.y, x.x, a.y));
  return a;
}

// direct 5-point DFT, forward (W5 = e^{-2pi i/5})
__device__ __forceinline__ void fft5(const float2 b[5], float2 z[5]) {
  const float2 w1 = make_float2( 0.309016994374947424f, -0.951056516295153572f);
  const float2 w2 = make_float2(-0.809016994374947424f, -0.587785252292473129f);
  const float2 w3 = make_float2(-0.809016994374947424f,  0.587785252292473129f);
  const float2 w4 = make_float2( 0.309016994374947424f,  0.951056516295153572f);
  z[0] = cadd(cadd(b[0], b[1]), cadd(cadd(b[2], b[3]), b[4]));
  z[1] = b[0]; z[1] = cxmad(z[1], w1, b[1]); z[1] = cxmad(z[1], w2, b[2]); z[1] = cxmad(z[1], w3, b[3]); z[1] = cxmad(z[1], w4, b[4]);
  z[2] = b[0]; z[2] = cxmad(z[2], w2, b[1]); z[2] = cxmad(z[2], w4, b[2]); z[2] = cxmad(z[2], w1, b[3]); z[2] = cxmad(z[2], w3, b[4]);
  z[3] = b[0]; z[3] = cxmad(z[3], w3, b[1]); z[3] = cxmad(z[3], w1, b[2]); z[3] = cxmad(z[3], w4, b[3]); z[3] = cxmad(z[3], w2, b[4]);
  z[4] = b[0]; z[4] = cxmad(z[4], w4, b[1]); z[4] = cxmad(z[4], w3, b[2]); z[4] = cxmad(z[4], w2, b[3]); z[4] = cxmad(z[4], w1, b[4]);
}

// NF interleaved register FFT-640s of zero-padded sequences (n1=0..4 live).
// Returns k2 = bitrev6(lane); v[f][k1] = X_f[k1 + 10*k2].
template <int NF>
__device__ __forceinline__ int fft640_regN(const float2 b[NF][5], float2 v[NF][10],
                                           int lane) {
  const float2 t1 = make_float2( 0.809016994374947424f, -0.587785252292473129f); // W10^1
  const float2 t2 = make_float2( 0.309016994374947424f, -0.951056516295153572f); // W10^2
  const float2 t3 = make_float2(-0.309016994374947424f, -0.951056516295153572f); // W10^3
  const float2 t4 = make_float2(-0.809016994374947424f, -0.587785252292473129f); // W10^4
#pragma unroll
  for (int f = 0; f < NF; f++) {
    float2 e[5], o[5], bp[5];
    fft5(b[f], e);
    bp[0] = b[f][0]; bp[1] = cmul(b[f][1], t1); bp[2] = cmul(b[f][2], t2);
    bp[3] = cmul(b[f][3], t3); bp[4] = cmul(b[f][4], t4);
    fft5(bp, o);
    v[f][0] = e[0]; v[f][2] = e[1]; v[f][4] = e[2]; v[f][6] = e[3]; v[f][8] = e[4];
    v[f][1] = o[0]; v[f][3] = o[1]; v[f][5] = o[2]; v[f][7] = o[3]; v[f][9] = o[4];
  }
  // twiddle: v[f][k1] *= W640^{lane*k1}
  float sn, cs;
  __sincosf(-2.0f * PI_F * (float)lane * (1.0f / 640.0f), &sn, &cs);
  float2 w1 = make_float2(cs, sn), wk = w1;
#pragma unroll
  for (int k = 1; k < 10; k++) {
#pragma unroll
    for (int f = 0; f < NF; f++) v[f][k] = cmul(v[f][k], wk);
    if (k < 9) wk = cmul(wk, w1);
  }
  // cross-lane FFT-64 over n2=lane: DIF radix-2, 6 shuffle stages, bitrev output.
#pragma unroll
  for (int s = 5; s >= 1; s--) {
    int half = 1 << s;
    int up = lane & half;
    float ang = -(PI_F / (float)half) * (float)(lane & (half - 1));
    float ss, cc;
    __sincosf(ang, &ss, &cc);
    float sgn = up ? -1.0f : 1.0f;
    float2 twl = make_float2(up ? cc : 1.0f, up ? ss : 0.0f);
#pragma unroll
    for (int f = 0; f < NF; f++)
#pragma unroll
      for (int q = 0; q < 10; q++) {
        float2 oth;
        oth.x = __shfl_xor(v[f][q].x, half, 64);
        oth.y = __shfl_xor(v[f][q].y, half, 64);
        float2 t = make_float2(fmaf(sgn, v[f][q].x, oth.x), fmaf(sgn, v[f][q].y, oth.y));
        v[f][q] = cmul(t, twl);
      }
  }
  {  // final stage half=1: twiddle is identity everywhere — adds/subs only
    float sgn = (lane & 1) ? -1.0f : 1.0f;
#pragma unroll
    for (int f = 0; f < NF; f++)
#pragma unroll
      for (int q = 0; q < 10; q++) {
        float2 oth;
        oth.x = __shfl_xor(v[f][q].x, 1, 64);
        oth.y = __shfl_xor(v[f][q].y, 1, 64);
        v[f][q] = make_float2(fmaf(sgn, v[f][q].x, oth.x), fmaf(sgn, v[f][q].y, oth.y));
      }
  }
  return __brev(lane) >> 26;
}

// ---- stage A: ALL phases. 16 rows/block; 4 waves x 2 iterations x 2 interleaved
// FFTs, fp16 LDS staging, transposed write = full 64B lines. 1600 blocks x 256 ----
#define ASTR 709
__global__ __launch_bounds__(256) void stageA_kernel(const float* __restrict__ img,
                                                     uint32_t* __restrict__ AT) {
  __shared__ uint32_t lds[16 * ASTR];   // 45,376 B fp16-pairs
  int wv = threadIdx.x >> 6, lane = threadIdx.x & 63;
  int bx = blockIdx.x;
  int p = bx / (NIMG * 20);
  int rem = bx - p * (NIMG * 20);
  int i = rem / 20, hg = rem - i * 20;
  int h0 = hg * 16;
  const float2* base = (const float2*)img + (size_t)(p * NIMG + i) * NH * NH;
  // w-apodization is row-invariant: compute the 5 lane scales once
  float aw[5];
#pragma unroll
  for (int j = 0; j < 5; j++) aw[j] = apodf(lane + 64 * j) * (1.0f / 640.0f);
  // 2 iterations x 2 interleaved row FFTs per wave: rows r = wv*4 + 2t + {0,1}
#pragma unroll 1
  for (int t = 0; t < 2; t++) {
    int r0 = wv * 4 + 2 * t;
    float2 b[2][5];
#pragma unroll
    for (int f = 0; f < 2; f++) {
      int h = h0 + r0 + f;
      const float2* src = base + (size_t)h * NH;
      float ah = apodf(h);
#pragma unroll
      for (int j = 0; j < 5; j++) {
        float2 x = src[lane + 64 * j];
        float sc = aw[j] * ah;
        b[f][j] = make_float2(x.x * sc, x.y * sc);
      }
    }
    float2 v[2][10];
    int k2 = fft640_regN<2>(b, v, lane);
#pragma unroll
    for (int f = 0; f < 2; f++) {
      uint32_t* rowl = lds + (r0 + f) * ASTR + 11 * k2;  // max 702 < 709
#pragma unroll
      for (int k = 0; k < 10; k++) rowl[k] = f2_to_h2(v[f][k]);
    }
  }
  __syncthreads();
  // transposed write: AT[kw][h0+c], c = tid&15 -> 16 consecutive h = 64B line
  int c = threadIdx.x & 15, kwv = threadIdx.x >> 4;   // kwv in [0,16)
  uint32_t* dst = AT + (size_t)(p * NIMG + i) * NK * NH + h0 + c;
  const uint32_t* srcl = lds + c * ASTR;
#pragma unroll
  for (int s = 0; s < 40; s++) {
    int kw = kwv + 16 * s;
    int q2 = (kw * 6554) >> 16;     // kw/10 (exact for kw<1638)
    int q1 = kw - 10 * q2;
    dst[(size_t)kw * NH] = srcl[11 * q2 + q1];
  }
}

// ---- taps: per (phase, point): kh weights[6], kw weights[6], phase (c,s) in tapw
// (stride 16 floats); [kh_base, kw_idx[6], pad] in tapi (stride 8 ints, int4x2) ----
__global__ __launch_bounds__(256) void taps_kernel(const float* __restrict__ traj,
                                                   float* __restrict__ tapw,
                                                   int* __restrict__ tapi) {
  int t = blockIdx.x * 256 + threadIdx.x;
  if (t >= NPH * KLEN) return;
  int p = t / KLEN, l = t - p * KLEN;
  float inv_i0a = 1.0f / i0f(KB_ALPHA);
  float* wout = tapw + (size_t)t * 16;
  int* iout = tapi + (size_t)t * 8;
  float ang = 0.0f;
#pragma unroll
  for (int d = 0; d < 2; d++) {
    float om = traj[((size_t)p * 2 + d) * KLEN + l];
    float tt = om * 640.0f / 6.28318530717958647692f;
    float base = floorf(tt - 3.0f);
    ang += om * 160.0f;              // n_shift = 320//2
    if (d == 0) {                    // kh: store base index only (taps consecutive)
      int bi = (int)base + 1 + 640;  // [318, 958]
      if (bi >= 640) bi -= 640;      // [0, 639]
      iout[0] = bi;
    }
#pragma unroll
    for (int j = 0; j < 6; j++) {
      float kf = base + (float)(j + 1);
      float u = tt - kf;
      float arg = fmaxf(1.0f - (u * u) * (1.0f / 9.0f), 0.0f);
      wout[d * 6 + j] = i0f(KB_ALPHA * sqrtf(arg)) * inv_i0a;
      if (d == 1) {                  // kw: individually wrapped indices
        int ki = (int)kf + 640;
        if (ki >= 640) ki -= 640;
        iout[1 + j] = ki;
      }
    }
  }
  float s, c;
  sincosf(ang, &s, &c);              // accurate path: |ang| up to ~1005 rad
  wout[12] = c;
  wout[13] = s;
  wout[14] = 0.f;
  wout[15] = 0.f;
  iout[7] = 0;
}

// ---- half-phase fused ladder kernel. Step encoding: s = phase*2 + half.
// blocks [0,BBLK2):          stageB(sb) — 8 images (1/XCD) -> Gw
// blocks [BBLK2,BBLK2+IBLK2): interp(si) — 8 images (1/XCD) from Gr
// sb<0 / si<0 disable a half. XCD pinning: image i = (bx&7) + 8*(step&1). ----
__global__ __launch_bounds__(256) void fusedBI_kernel(
    const uint32_t* __restrict__ AT, uint32_t* __restrict__ Gw,
    const uint32_t* __restrict__ Gr, const float* __restrict__ tapw,
    const int* __restrict__ tapi, float* __restrict__ out, int sb, int si) {
  if (blockIdx.x < BBLK2) {
    // ---------------- stageB half (1 col/wave) ----------------
    if (sb < 0) return;
    int wv = threadIdx.x >> 6, lane = threadIdx.x & 63;
    int x = blockIdx.x & 7;
    int J = blockIdx.x >> 3;         // 0..159
    int pb = sb >> 1;
    int i = x + 8 * (sb & 1);
    int kw = J * 4 + wv;
    const uint32_t* rowp = AT + ((size_t)(pb * NIMG + i) * NK + kw) * NH;  // contiguous
    float2 b[1][5];
#pragma unroll
    for (int j = 0; j < 5; j++) b[0][j] = h2_to_f2(rowp[lane + 64 * j]);
    float2 v[1][10];
    int k2 = fft640_regN<1>(b, v, lane);
    uint32_t hv[10];
#pragma unroll
    for (int k = 0; k < 10; k++) hv[k] = f2_to_h2(v[0][k]);
    uint32_t* rowo = Gw + ((size_t)i * NK + kw) * NKP;
    uint2* dst = (uint2*)(rowo + 10 * k2);
#pragma unroll
    for (int m = 0; m < 5; m++) dst[m] = make_uint2(hv[2 * m], hv[2 * m + 1]);
    if (k2 == 0) {                   // mirror kh 0..5 at 640..645 (no wrap in interp)
      uint2* pd = (uint2*)(rowo + 640);
#pragma unroll
      for (int m = 0; m < 3; m++) pd[m] = make_uint2(hv[2 * m], hv[2 * m + 1]);
    }
  } else {
    // ---------------- interp half ----------------
    if (si < 0) return;
    int bx = blockIdx.x - BBLK2;     // 0..503; BBLK2%8==0 keeps XCD = blockIdx&7
    int x = bx & 7;
    int q = ((bx >> 3) << 8) + threadIdx.x;   // 0..16127
    if (q >= KLEN) return;
    int pi = si >> 1;
    int i = x + 8 * (si & 1);
    int l = q;
    const float4* w4 = (const float4*)(tapw + (size_t)(pi * KLEN + l) * 16);
    float4 wa = w4[0], wb = w4[1], wc = w4[2], wd = w4[3];
    const int4* i4 = (const int4*)(tapi + (size_t)(pi * KLEN + l) * 8);
    int4 ia = i4[0], ib = i4[1];
    float whv[6] = {wa.x, wa.y, wa.z, wa.w, wb.x, wb.y};
    float wwv[6] = {wb.z, wb.w, wc.x, wc.y, wc.z, wc.w};
    int   iwv[6] = {ia.y, ia.z, ia.w, ib.x, ib.y, ib.z};
    int   b0 = ia.x;
    int   e = b0 & ~1, off = b0 & 1;
    // 7-wide shifted kh-weight window (off=0: w0..w5 at 0..5; off=1: at 1..6)
    float we[7];
    we[0] = off ? 0.f    : whv[0];
    we[1] = off ? whv[0] : whv[1];
    we[2] = off ? whv[1] : whv[2];
    we[3] = off ? whv[2] : whv[3];
    we[4] = off ? whv[3] : whv[4];
    we[5] = off ? whv[4] : whv[5];
    we[6] = off ? whv[5] : 0.f;
    const uint32_t* g = Gr + (size_t)i * (NK * NKP) + e;
    uint2 raw[6][4];
#pragma unroll
    for (int jw = 0; jw < 6; jw++) {
      const uint2* col = (const uint2*)(g + iwv[jw] * NKP);
#pragma unroll
      for (int m = 0; m < 4; m++) raw[jw][m] = col[m];
    }
    __builtin_amdgcn_sched_barrier(0);   // don't sink loads into the FMA chain
    float ar = 0.f, ai = 0.f;
#pragma unroll
    for (int jw = 0; jw < 6; jw++) {
      float sr = 0.f, si2 = 0.f;
#pragma unroll
      for (int k = 0; k < 7; k++) {
        uint32_t u = (k & 1) ? raw[jw][k >> 1].y : raw[jw][k >> 1].x;
        float2 v = h2_to_f2(u);
        sr = fmaf(we[k], v.x, sr);
        si2 = fmaf(we[k], v.y, si2);
      }
      ar = fmaf(wwv[jw], sr, ar);
      ai = fmaf(wwv[jw], si2, ai);
    }
    float c = wd.x, s = wd.y;
    size_t o = (size_t)(pi * NIMG + i) * KLEN + l;
    ((float2*)out)[o] = make_float2(ar * c - ai * s, ar * s + ai * c);
  }
}

extern "C" void kernel_launch(void* const* d_in, const int* in_sizes, int n_in,
                              void* d_out, int out_size, void* d_ws, size_t ws_size,
                              hipStream_t stream) {
  const float* img  = (const float*)d_in[0];   // (1,5,8,2,320,320,2) f32
  const float* traj = (const float*)d_in[1];   // (5,2,16000) f32
  float* out = (float*)d_out;                  // (1,5,8,2,16000,2) f32

  char* ws = (char*)d_ws;
  float*    tapw = (float*)ws;                       // 5*16000*16*4 = 5,120,000 B
  int*      tapi = (int*)(ws + 5120000);             // 5*16000* 8*4 = 2,560,000 B
  uint32_t* AT   = (uint32_t*)(ws + 8960000);        // 80*640*320*4 = 65,536,000 B (fp16)
  const size_t Goff = 8960000 + 65536000;            // 74,496,000
  const size_t Gb   = (size_t)NIMG * NK * NKP * 4;   // 26,542,080 B (fp16, padded rows)
  // per-phase G buffers (needed by the ladder). Branch depends only on ws_size
  // -> identical work every call (graph-safe). Total need: ~207 MB.
  bool has5 = (ws_size >= Goff + 5 * Gb);

  taps_kernel<<<(NPH * KLEN + 255) / 256, 256, 0, stream>>>(traj, tapw, tapi);
  stageA_kernel<<<NPH * NIMG * 20, 256, 0, stream>>>(img, AT);
  if (has5) {
    // half-phase ladder: launch s runs stageB(step s) + interp(step s-1)
    for (int s = 0; s <= 2 * NPH; s++) {
      int sb = (s < 2 * NPH) ? s : -1;
      int si = (s > 0) ? s - 1 : -1;
      uint32_t* Gw = (uint32_t*)(ws + Goff + (size_t)((sb >= 0) ? (sb >> 1) : 0) * Gb);
      uint32_t* Gr = (uint32_t*)(ws + Goff + (size_t)((si >= 0) ? (si >> 1) : 0) * Gb);
      fusedBI_kernel<<<BBLK2 + IBLK2, 256, 0, stream>>>(AT, Gw, Gr, tapw, tapi, out,
                                                        sb, si);
    }
  } else {
    // fallback: single G buffer, strictly sequential B then I per half-phase
    uint32_t* G0 = (uint32_t*)(ws + Goff);
    for (int s = 0; s < 2 * NPH; s++) {
      fusedBI_kernel<<<BBLK2 + IBLK2, 256, 0, stream>>>(AT, G0, G0, tapw, tapi, out,
                                                        s, -1);
      fusedBI_kernel<<<BBLK2 + IBLK2, 256, 0, stream>>>(AT, G0, G0, tapw, tapi, out,
                                                        -1, s);
    }
  }
}

// Round 15
// 255.205 us; speedup vs baseline: 1.4172x; 1.1248x over previous
//
#include <hip/hip_runtime.h>
#include <hip/hip_fp16.h>
#include <cstdint>
#include <cstddef>

// NUFFT type-2, torchkbnufft-compatible (J=6, alpha=14.04, os=2).
// Pipeline (5 phases, 16 coil-images each, 320x320 -> 640x640), 4 launches:
//   taps:   KB weights + [kh_base, 6 wrapped kw indices] per (phase,point)
//   stageA: ALL phases, apodize+pad rows, reg-FFT-640 along W -> AT[pi][kw][h] fp16.
//           256t blocks, 16 rows/block, 4 waves x 2 iter x 2 interleaved FFTs.
//   stageB: ALL phases, col FFTs -> G2[p][kw][kh][img] fp16 IMAGE-INTERLEAVED.
//           1024t block = one kw: 16 waves = 16 images, LDS transpose
//           (640 kh x 16 img, row stride 17), block writes 40.9KB contiguous.
//   interp: ALL phases. R14 diagnosis: old per-image layout made interp
//           per-XCD-L2-LINE-bandwidth-bound (384B of 64B-lines per point-image;
//           98MB/phase / (4.3TB/s per XCD) = 23us/phase, exactly measured).
//           G2 interleaving puts all 16 images of a tap in ONE 64B line:
//           lane-quad (4 lanes = 1 point) loads uint4 each (4 images), line
//           fully consumed. 37MB/phase of line traffic from L3 (~14TB/s).
// FFT-640 = four-step 10x64 in registers: zero-padded FFT-10 (2x FFT-5), twiddle,
// 6 __shfl_xor butterfly stages with sign-fold + lane-conditional twiddle.
// fp16 storage: rel err ~5e-4 << 4.06e-2 threshold (measured absmax 0.0078).

#define PI_F     3.14159265358979323846f
#define KB_ALPHA 14.04f
#define NPH  5
#define NIMG 16
#define NH   320
#define NK   640
#define KLEN 16000

__device__ __forceinline__ uint32_t f2_to_h2(float2 v) {
  union { __half2 h; uint32_t u; } cv;
  cv.h = __float22half2_rn(v);
  return cv.u;
}
__device__ __forceinline__ float2 h2_to_f2(uint32_t u) {
  union { uint32_t u; __half2 h; } cv;
  cv.u = u;
  return __half22float2(cv.h);
}

// ---- modified Bessel I0 (A&S 9.8.1 / 9.8.2, rel err ~2e-7). I0(alpha) cancels
// between apodization (numerator) and tap weights (denominator). ----
__device__ __forceinline__ float i0f(float x) {
  if (x < 3.75f) {
    float t = x * (1.0f / 3.75f), t2 = t * t;
    return 1.0f + t2 * (3.5156229f + t2 * (3.0899424f + t2 * (1.2067492f +
                 t2 * (0.2659732f + t2 * (0.0360768f + t2 * 0.0045813f)))));
  }
  float t = 3.75f / x;
  float poly = 0.39894228f + t * (0.01328592f + t * (0.00225319f + t * (-0.00157565f +
               t * (0.00916281f + t * (-0.02057706f + t * (0.02635537f +
               t * (-0.01647633f + t * 0.00392377f)))))));
  return expf(x) * rsqrtf(x) * poly;
}

// apodization scale (1/FT(KB)); z^2 = alpha^2-(pi*J*u)^2 > 0 always for |u|<=0.25
__device__ __forceinline__ float apodf(int n) {
  float u = (float)(n - 160) * (1.0f / 640.0f);
  float pj = PI_F * 6.0f * u;
  float z = sqrtf(KB_ALPHA * KB_ALPHA - pj * pj);
  float sh = 0.5f * (expf(z) - expf(-z));     // sinh(z)
  return z * i0f(KB_ALPHA) / (6.0f * sh);     // 1/ft = z*I0a/(J*sinh z)
}

__device__ __forceinline__ float2 cadd(float2 a, float2 b) { return make_float2(a.x + b.x, a.y + b.y); }
__device__ __forceinline__ float2 cmul(float2 a, float2 b) {
  return make_float2(fmaf(a.x, b.x, -a.y * b.y), fmaf(a.x, b.y, a.y * b.x));
}
__device__ __forceinline__ float2 cxmad(float2 a, float2 w, float2 x) {
  a.x = fmaf(w.x, x.x, fmaf(-w.y, x.y, a.x));
  a.y = fmaf(w.x, x.y, fmaf( w.y, x.x, a.y));
  return a;
}

// direct 5-point DFT, forward (W5 = e^{-2pi i/5})
__device__ __forceinline__ void fft5(const float2 b[5], float2 z[5]) {
  const float2 w1 = make_float2( 0.309016994374947424f, -0.951056516295153572f);
  const float2 w2 = make_float2(-0.809016994374947424f, -0.587785252292473129f);
  const float2 w3 = make_float2(-0.809016994374947424f,  0.587785252292473129f);
  const float2 w4 = make_float2( 0.309016994374947424f,  0.951056516295153572f);
  z[0] = cadd(cadd(b[0], b[1]), cadd(cadd(b[2], b[3]), b[4]));
  z[1] = b[0]; z[1] = cxmad(z[1], w1, b[1]); z[1] = cxmad(z[1], w2, b[2]); z[1] = cxmad(z[1], w3, b[3]); z[1] = cxmad(z[1], w4, b[4]);
  z[2] = b[0]; z[2] = cxmad(z[2], w2, b[1]); z[2] = cxmad(z[2], w4, b[2]); z[2] = cxmad(z[2], w1, b[3]); z[2] = cxmad(z[2], w3, b[4]);
  z[3] = b[0]; z[3] = cxmad(z[3], w3, b[1]); z[3] = cxmad(z[3], w1, b[2]); z[3] = cxmad(z[3], w4, b[3]); z[3] = cxmad(z[3], w2, b[4]);
  z[4] = b[0]; z[4] = cxmad(z[4], w4, b[1]); z[4] = cxmad(z[4], w3, b[2]); z[4] = cxmad(z[4], w2, b[3]); z[4] = cxmad(z[4], w1, b[4]);
}

// NF interleaved register FFT-640s of zero-padded sequences (n1=0..4 live).
// Returns k2 = bitrev6(lane); v[f][k1] = X_f[k1 + 10*k2].
template <int NF>
__device__ __forceinline__ int fft640_regN(const float2 b[NF][5], float2 v[NF][10],
                                           int lane) {
  const float2 t1 = make_float2( 0.809016994374947424f, -0.587785252292473129f); // W10^1
  const float2 t2 = make_float2( 0.309016994374947424f, -0.951056516295153572f); // W10^2
  const float2 t3 = make_float2(-0.309016994374947424f, -0.951056516295153572f); // W10^3
  const float2 t4 = make_float2(-0.809016994374947424f, -0.587785252292473129f); // W10^4
#pragma unroll
  for (int f = 0; f < NF; f++) {
    float2 e[5], o[5], bp[5];
    fft5(b[f], e);
    bp[0] = b[f][0]; bp[1] = cmul(b[f][1], t1); bp[2] = cmul(b[f][2], t2);
    bp[3] = cmul(b[f][3], t3); bp[4] = cmul(b[f][4], t4);
    fft5(bp, o);
    v[f][0] = e[0]; v[f][2] = e[1]; v[f][4] = e[2]; v[f][6] = e[3]; v[f][8] = e[4];
    v[f][1] = o[0]; v[f][3] = o[1]; v[f][5] = o[2]; v[f][7] = o[3]; v[f][9] = o[4];
  }
  // twiddle: v[f][k1] *= W640^{lane*k1}
  float sn, cs;
  __sincosf(-2.0f * PI_F * (float)lane * (1.0f / 640.0f), &sn, &cs);
  float2 w1 = make_float2(cs, sn), wk = w1;
#pragma unroll
  for (int k = 1; k < 10; k++) {
#pragma unroll
    for (int f = 0; f < NF; f++) v[f][k] = cmul(v[f][k], wk);
    if (k < 9) wk = cmul(wk, w1);
  }
  // cross-lane FFT-64 over n2=lane: DIF radix-2, 6 shuffle stages, bitrev output.
#pragma unroll
  for (int s = 5; s >= 1; s--) {
    int half = 1 << s;
    int up = lane & half;
    float ang = -(PI_F / (float)half) * (float)(lane & (half - 1));
    float ss, cc;
    __sincosf(ang, &ss, &cc);
    float sgn = up ? -1.0f : 1.0f;
    float2 twl = make_float2(up ? cc : 1.0f, up ? ss : 0.0f);
#pragma unroll
    for (int f = 0; f < NF; f++)
#pragma unroll
      for (int q = 0; q < 10; q++) {
        float2 oth;
        oth.x = __shfl_xor(v[f][q].x, half, 64);
        oth.y = __shfl_xor(v[f][q].y, half, 64);
        float2 t = make_float2(fmaf(sgn, v[f][q].x, oth.x), fmaf(sgn, v[f][q].y, oth.y));
        v[f][q] = cmul(t, twl);
      }
  }
  {  // final stage half=1: twiddle is identity everywhere — adds/subs only
    float sgn = (lane & 1) ? -1.0f : 1.0f;
#pragma unroll
    for (int f = 0; f < NF; f++)
#pragma unroll
      for (int q = 0; q < 10; q++) {
        float2 oth;
        oth.x = __shfl_xor(v[f][q].x, 1, 64);
        oth.y = __shfl_xor(v[f][q].y, 1, 64);
        v[f][q] = make_float2(fmaf(sgn, v[f][q].x, oth.x), fmaf(sgn, v[f][q].y, oth.y));
      }
  }
  return __brev(lane) >> 26;
}

// ---- stage A: ALL phases. 16 rows/block; 4 waves x 2 iterations x 2 interleaved
// FFTs, fp16 LDS staging, transposed write = full 64B lines. 1600 blocks x 256 ----
#define ASTR 709
__global__ __launch_bounds__(256) void stageA_kernel(const float* __restrict__ img,
                                                     uint32_t* __restrict__ AT) {
  __shared__ uint32_t lds[16 * ASTR];   // 45,376 B fp16-pairs
  int wv = threadIdx.x >> 6, lane = threadIdx.x & 63;
  int bx = blockIdx.x;
  int p = bx / (NIMG * 20);
  int rem = bx - p * (NIMG * 20);
  int i = rem / 20, hg = rem - i * 20;
  int h0 = hg * 16;
  const float2* base = (const float2*)img + (size_t)(p * NIMG + i) * NH * NH;
  // w-apodization is row-invariant: compute the 5 lane scales once
  float aw[5];
#pragma unroll
  for (int j = 0; j < 5; j++) aw[j] = apodf(lane + 64 * j) * (1.0f / 640.0f);
  // 2 iterations x 2 interleaved row FFTs per wave: rows r = wv*4 + 2t + {0,1}
#pragma unroll 1
  for (int t = 0; t < 2; t++) {
    int r0 = wv * 4 + 2 * t;
    float2 b[2][5];
#pragma unroll
    for (int f = 0; f < 2; f++) {
      int h = h0 + r0 + f;
      const float2* src = base + (size_t)h * NH;
      float ah = apodf(h);
#pragma unroll
      for (int j = 0; j < 5; j++) {
        float2 x = src[lane + 64 * j];
        float sc = aw[j] * ah;
        b[f][j] = make_float2(x.x * sc, x.y * sc);
      }
    }
    float2 v[2][10];
    int k2 = fft640_regN<2>(b, v, lane);
#pragma unroll
    for (int f = 0; f < 2; f++) {
      uint32_t* rowl = lds + (r0 + f) * ASTR + 11 * k2;  // max 702 < 709
#pragma unroll
      for (int k = 0; k < 10; k++) rowl[k] = f2_to_h2(v[f][k]);
    }
  }
  __syncthreads();
  // transposed write: AT[kw][h0+c], c = tid&15 -> 16 consecutive h = 64B line
  int c = threadIdx.x & 15, kwv = threadIdx.x >> 4;   // kwv in [0,16)
  uint32_t* dst = AT + (size_t)(p * NIMG + i) * NK * NH + h0 + c;
  const uint32_t* srcl = lds + c * ASTR;
#pragma unroll
  for (int s = 0; s < 40; s++) {
    int kw = kwv + 16 * s;
    int q2 = (kw * 6554) >> 16;     // kw/10 (exact for kw<1638)
    int q1 = kw - 10 * q2;
    dst[(size_t)kw * NH] = srcl[11 * q2 + q1];
  }
}

// ---- stage B: column FFTs -> image-interleaved G2[lp][kw][kh][img] fp16.
// Block (1024 thr) = one (phase, kw): wave wv FFTs image wv's column; LDS
// transpose rows=kh (stride 17 -> <=4-way store conflicts, free read), then
// 10 fully-coalesced passes write 40,960B contiguous. grid = nph*640. ----
__global__ __launch_bounds__(1024) void stageB_kernel(const uint32_t* __restrict__ AT,
                                                      uint32_t* __restrict__ G2,
                                                      int p0) {
  __shared__ uint32_t lds[NK * 17];   // 43,520 B
  int wv = threadIdx.x >> 6, lane = threadIdx.x & 63;
  int kw = blockIdx.x % NK;
  int lp = blockIdx.x / NK;
  int p = p0 + lp;
  const uint32_t* rowp = AT + ((size_t)(p * NIMG + wv) * NK + kw) * NH;  // contiguous
  float2 b[1][5];
#pragma unroll
  for (int j = 0; j < 5; j++) b[0][j] = h2_to_f2(rowp[lane + 64 * j]);
  float2 v[1][10];
  int k2 = fft640_regN<1>(b, v, lane);
  // lds[kh][img]: kh = 10*k2 + k, row stride 17
  uint32_t* base = lds + wv;
#pragma unroll
  for (int k = 0; k < 10; k++) base[(10 * k2 + k) * 17] = f2_to_h2(v[0][k]);
  __syncthreads();
  // write pass: 10,240 consecutive uint32 = G2[lp][kw][*][*]
  uint32_t* dst = G2 + ((size_t)lp * NK + kw) * (NK * NIMG);
#pragma unroll
  for (int n = 0; n < 10; n++) {
    int f = n * 1024 + threadIdx.x;
    dst[f] = lds[(f >> 4) * 17 + (f & 15)];
  }
}

// ---- taps: per (phase, point): kh weights[6], kw weights[6], phase (c,s) in tapw
// (stride 16 floats); [kh_base, kw_idx[6], pad] in tapi (stride 8 ints, int4x2) ----
__global__ __launch_bounds__(256) void taps_kernel(const float* __restrict__ traj,
                                                   float* __restrict__ tapw,
                                                   int* __restrict__ tapi) {
  int t = blockIdx.x * 256 + threadIdx.x;
  if (t >= NPH * KLEN) return;
  int p = t / KLEN, l = t - p * KLEN;
  float inv_i0a = 1.0f / i0f(KB_ALPHA);
  float* wout = tapw + (size_t)t * 16;
  int* iout = tapi + (size_t)t * 8;
  float ang = 0.0f;
#pragma unroll
  for (int d = 0; d < 2; d++) {
    float om = traj[((size_t)p * 2 + d) * KLEN + l];
    float tt = om * 640.0f / 6.28318530717958647692f;
    float base = floorf(tt - 3.0f);
    ang += om * 160.0f;              // n_shift = 320//2
    if (d == 0) {                    // kh: store base index (taps consecutive mod 640)
      int bi = (int)base + 1 + 640;  // [318, 958]
      if (bi >= 640) bi -= 640;      // [0, 639]
      iout[0] = bi;
    }
#pragma unroll
    for (int j = 0; j < 6; j++) {
      float kf = base + (float)(j + 1);
      float u = tt - kf;
      float arg = fmaxf(1.0f - (u * u) * (1.0f / 9.0f), 0.0f);
      wout[d * 6 + j] = i0f(KB_ALPHA * sqrtf(arg)) * inv_i0a;
      if (d == 1) {                  // kw: individually wrapped indices
        int ki = (int)kf + 640;
        if (ki >= 640) ki -= 640;
        iout[1 + j] = ki;
      }
    }
  }
  float s, c;
  sincosf(ang, &s, &c);              // accurate path: |ang| up to ~1005 rad
  wout[12] = c;
  wout[13] = s;
  wout[14] = 0.f;
  wout[15] = 0.f;
  iout[7] = 0;
}

// ---- interp from image-interleaved G2. Block 256 thr = 64 points x 4 image-
// groups: lane-quad (q=tid&3) covers one point; thread accumulates images
// 4q..4q+3 via uint4 loads (quad -> one full 64B line per tap). Two 18-load
// batches keep MLP high at ~130 VGPR. grid = nph*250. ----
__global__ __launch_bounds__(256) void interp_kernel(const uint32_t* __restrict__ G2,
                                                     const float* __restrict__ tapw,
                                                     const int* __restrict__ tapi,
                                                     float* __restrict__ out, int p0) {
  int lp = blockIdx.x / 250;
  int bb = blockIdx.x % 250;
  int p = p0 + lp;
  int m = threadIdx.x >> 2, q = threadIdx.x & 3;
  int l = bb * 64 + m;
  int img0 = q * 4;
  const float4* w4 = (const float4*)(tapw + (size_t)(p * KLEN + l) * 16);
  float4 wa = w4[0], wb = w4[1], wc = w4[2], wd = w4[3];
  const int4* i4 = (const int4*)(tapi + (size_t)(p * KLEN + l) * 8);
  int4 ia = i4[0], ib = i4[1];
  float whv[6] = {wa.x, wa.y, wa.z, wa.w, wb.x, wb.y};
  float wwv[6] = {wb.z, wb.w, wc.x, wc.y, wc.z, wc.w};
  int   iwv[6] = {ia.y, ia.z, ia.w, ib.x, ib.y, ib.z};
  int   b0 = ia.x;
  int kh[6];
#pragma unroll
  for (int j = 0; j < 6; j++) {
    int v = b0 + j;
    kh[j] = (v >= NK) ? v - NK : v;
  }
  const uint32_t* g = G2 + (size_t)lp * NK * NK * NIMG + img0;
  float2 acc[4];
#pragma unroll
  for (int j = 0; j < 4; j++) acc[j] = make_float2(0.f, 0.f);
#pragma unroll 1
  for (int half = 0; half < 2; half++) {
    uint4 raw[18];
#pragma unroll
    for (int jw2 = 0; jw2 < 3; jw2++) {
      int cb = iwv[half * 3 + jw2] * NK;
#pragma unroll
      for (int jh = 0; jh < 6; jh++)
        raw[jw2 * 6 + jh] = *(const uint4*)(g + (size_t)(cb + kh[jh]) * NIMG);
    }
    __builtin_amdgcn_sched_barrier(0);   // keep all 18 loads in flight
#pragma unroll
    for (int jw2 = 0; jw2 < 3; jw2++) {
      float2 cs[4];
#pragma unroll
      for (int j = 0; j < 4; j++) cs[j] = make_float2(0.f, 0.f);
#pragma unroll
      for (int jh = 0; jh < 6; jh++) {
        uint4 u = raw[jw2 * 6 + jh];
        float w = whv[jh];
        float2 v0 = h2_to_f2(u.x), v1 = h2_to_f2(u.y);
        float2 v2 = h2_to_f2(u.z), v3 = h2_to_f2(u.w);
        cs[0].x = fmaf(w, v0.x, cs[0].x); cs[0].y = fmaf(w, v0.y, cs[0].y);
        cs[1].x = fmaf(w, v1.x, cs[1].x); cs[1].y = fmaf(w, v1.y, cs[1].y);
        cs[2].x = fmaf(w, v2.x, cs[2].x); cs[2].y = fmaf(w, v2.y, cs[2].y);
        cs[3].x = fmaf(w, v3.x, cs[3].x); cs[3].y = fmaf(w, v3.y, cs[3].y);
      }
      float ww = wwv[half * 3 + jw2];
#pragma unroll
      for (int j = 0; j < 4; j++) {
        acc[j].x = fmaf(ww, cs[j].x, acc[j].x);
        acc[j].y = fmaf(ww, cs[j].y, acc[j].y);
      }
    }
  }
  float c = wd.x, s = wd.y;
#pragma unroll
  for (int j = 0; j < 4; j++) {
    size_t o = (size_t)(p * NIMG + img0 + j) * KLEN + l;
    ((float2*)out)[o] = make_float2(acc[j].x * c - acc[j].y * s,
                                    acc[j].x * s + acc[j].y * c);
  }
}

extern "C" void kernel_launch(void* const* d_in, const int* in_sizes, int n_in,
                              void* d_out, int out_size, void* d_ws, size_t ws_size,
                              hipStream_t stream) {
  const float* img  = (const float*)d_in[0];   // (1,5,8,2,320,320,2) f32
  const float* traj = (const float*)d_in[1];   // (5,2,16000) f32
  float* out = (float*)d_out;                  // (1,5,8,2,16000,2) f32

  char* ws = (char*)d_ws;
  float*    tapw = (float*)ws;                       // 5*16000*16*4 = 5,120,000 B
  int*      tapi = (int*)(ws + 5120000);             // 5*16000* 8*4 = 2,560,000 B
  uint32_t* AT   = (uint32_t*)(ws + 8960000);        // 80*640*320*4 = 65,536,000 B (fp16)
  const size_t Goff = 8960000 + 65536000;            // 74,496,000
  const size_t Gb   = (size_t)NK * NK * NIMG * 4;    // 26,214,400 B per phase
  // all-phase G2 if workspace allows (4-launch pipeline); else per-phase loop.
  // Branch depends only on ws_size -> identical work every call (graph-safe).
  bool has5 = (ws_size >= Goff + 5 * Gb);            // needs ~205.6 MB
  uint32_t* G2 = (uint32_t*)(ws + Goff);

  taps_kernel<<<(NPH * KLEN + 255) / 256, 256, 0, stream>>>(traj, tapw, tapi);
  stageA_kernel<<<NPH * NIMG * 20, 256, 0, stream>>>(img, AT);
  if (has5) {
    stageB_kernel<<<NPH * NK, 1024, 0, stream>>>(AT, G2, 0);
    interp_kernel<<<NPH * 250, 256, 0, stream>>>(G2, tapw, tapi, out, 0);
  } else {
    for (int p = 0; p < NPH; p++) {
      stageB_kernel<<<NK, 1024, 0, stream>>>(AT, G2, p);
      interp_kernel<<<250, 256, 0, stream>>>(G2, tapw, tapi, out, p);
    }
  }
}